// Round 6
// baseline (646.069 us; speedup 1.0000x reference)
//
#include <hip/hip_runtime.h>
#include <stdint.h>
#include <math.h>

#define N_CLS    81
#define TOPK     1000
#define LISTCAP  2031616u       // candidate key capacity (~2M; observed ~0.9-1.3M)
#define CAP2     16384          // final selection capacity
#define SCORE_TH 0.05f
#define IMG_W    1333.0f
#define IMG_H    800.0f

// fine histogram: bin = (float_bits >> 9) - FH_BASE, 512-ULP granularity.
// p in (0.05, 1.0]  =>  bits>>9 in [1961<<10 .. (2032<<10)+1024] -> 72705 bins
#define FH_BASE  (1961u << 10)
#define FH_BINS  73728          // 256 chunks x 288 bins (padded; memset-zeroed)

// workspace layout (byte offsets); total 16,831,424 B (< proven 17.1 MB map)
#define OFF_CNT    0                       // u32 total candidates
#define OFF_CNT2   8                       // u32 selected count
#define OFF_TICK1  16                      // u32 K1 done-ticket
#define OFF_TICK2  20                      // u32 K2 done-ticket
#define OFF_TICK3  24                      // u32 K3 done-ticket
#define OFF_TB     32                      // u32 exact threshold bits
#define OFF_FH     512                     // u32[FH_BINS] fine hist (294912 B)
#define MEMSET_BYTES 295424
#define OFF_SEL    295424                  // u64[LISTCAP] (16,252,928 B)
#define OFF_SEL2   16548352                // u64[CAP2] (131072 B)
#define OFF_BOX    16679424                // f32[1000*4] (16B-aligned)
#define OFF_SCORE  16695424                // f32[1000]
#define OFF_CLS    16699424                // i32[1000]
#define OFF_MASK   16703424                // u64[1000*16] conflict bit matrix

#define ROWS_PER_BLK 128
#define TILE_FLOATS  (ROWS_PER_BLK * N_CLS)   // 10368 floats = 41472 B
#define CBUF_CAP     1024

typedef unsigned long long u64;

// direct global->LDS 16B DMA (m97 pattern): LDS dest = wave-uniform base + lane*16
__device__ __forceinline__ void gload_lds16(const float* g, float* l) {
    __builtin_amdgcn_global_load_lds(
        (const __attribute__((address_space(1))) unsigned int*)g,
        (__attribute__((address_space(3))) unsigned int*)l, 16, 0, 0);
}

__device__ __forceinline__ unsigned agent_load_u32(const unsigned* p) {
    return __hip_atomic_load(p, __ATOMIC_RELAXED, __HIP_MEMORY_SCOPE_AGENT);
}
__device__ __forceinline__ u64 agent_load_u64(const u64* p) {
    return __hip_atomic_load(p, __ATOMIC_RELAXED, __HIP_MEMORY_SCOPE_AGENT);
}
__device__ __forceinline__ void agent_store_u64(u64* p, u64 v) {
    __hip_atomic_store(p, v, __ATOMIC_RELAXED, __HIP_MEMORY_SCOPE_AGENT);
}

// ------- K1: round-2 pass1 (proven 52us) + fine-hist + winner computes tb -------
// 128-row LDS tile via global_load_lds, 256 threads, pair-of-threads per row.
// Per-row math is VERBATIM the verified bit-exact form (class-parity pair split,
// bitrev5 stack tree, shfl_xor(1) for max and top-level sum association).
// Per candidate: one global atomicAdd into the flat 512-ULP fine hist (replaces
// the old coarse-hist + separate k_refine pass entirely). Last-ticket block
// suffix-scans the hist to the exact threshold tb.
__global__ __launch_bounds__(256) void k_pass1(
        const float* __restrict__ logits, int nrows,
        u64* __restrict__ sel, unsigned* __restrict__ cnt,
        unsigned* __restrict__ fhist, unsigned* __restrict__ tick,
        unsigned* __restrict__ ptb) {
    __shared__ float tile[TILE_FLOATS];
    __shared__ u64 cbuf[CBUF_CAP];
    __shared__ unsigned scs[256], ssfx[256];
    __shared__ unsigned lcnt, gbase, tkt, wex;
    __shared__ int wg;
    int tid = threadIdx.x, wv = tid >> 6, ln = tid & 63;
    if (tid == 0) lcnt = 0;

    int base = blockIdx.x * ROWS_PER_BLK;
    int nr = nrows - base; if (nr > ROWS_PER_BLK) nr = ROWS_PER_BLK;
    const float* gtile = logits + (size_t)base * N_CLS;

    if (nr == ROWS_PER_BLK) {
        // 10 iterations x 4 waves x 1KB = 40960 B coalesced direct-to-LDS
        #pragma unroll
        for (int it = 0; it < 10; ++it) {
            int c = it * 1024 + wv * 256;          // float offset, wave-uniform
            gload_lds16(gtile + c + ln * 4, tile + c);
        }
        if (tid < TILE_FLOATS - 10240) tile[10240 + tid] = gtile[10240 + tid];
    } else {
        for (int i = tid; i < nr * N_CLS; i += 256) tile[i] = gtile[i];
    }
    __syncthreads();   // drains vmcnt (global_load_lds) + lgkmcnt

    int r = tid >> 1, h = tid & 1;
    if (r < nr) {
        const int rb = r * N_CLS + h;              // first owned class in LDS
        float v[41];
        #pragma unroll
        for (int m = 0; m < 40; ++m) v[m] = tile[rb + 2 * m];
        v[40] = (h == 0) ? tile[rb + 80] : 0.0f;   // class 80 only exists for h=0

        // ---- row max (exact, order-free) ----
        float mx = v[0];
        #pragma unroll
        for (int m = 1; m < 40; ++m) mx = fmaxf(mx, v[m]);
        mx = fmaxf(mx, (h == 0) ? v[40] : v[0]);
        float om = __shfl_xor(mx, 1);
        float mrow = fmaxf(mx, om);

        // ---- exps (op-identical to reference kernel) ----
        #pragma unroll
        for (int m = 0; m < 40; ++m) v[m] = expf(v[m] - mrow);
        v[40] = (h == 0) ? expf(v[40] - mrow) : 0.0f;

        // ---- per-thread bitrev subtree over leaves l = h + 2*b ----
        float stk0 = 0.f, stk1 = 0.f, stk2 = 0.f, stk3 = 0.f, stk4 = 0.f;
        float S = 0.f;
        #pragma unroll
        for (int i = 0; i < 32; ++i) {
            const int b = ((i & 1) << 4) | ((i & 2) << 2) | (i & 4) |
                          ((i & 8) >> 2) | ((i & 16) >> 4);   // bitrev5(i)
            float x = v[b];
            if (b < 8) x += v[b + 32];
            else if (b == 8) x = (h == 0) ? x + v[40] : x;
            if (i & 1) { x = stk0 + x;
              if (i & 2) { x = stk1 + x;
                if (i & 4) { x = stk2 + x;
                  if (i & 8) { x = stk3 + x;
                    if (i & 16) { S = stk4 + x; } else stk4 = x;
                  } else stk3 = x;
                } else stk2 = x;
              } else stk1 = x;
            } else stk0 = x;
        }
        float oS = __shfl_xor(S, 1);
        float s = (h == 0) ? (S + oS) : (oS + S);  // exact top-level association

        // ---- emit: conservative pre-filter, then bit-exact p>0.05 ----
        float eth = 0.0499f * s;                   // 0.2% margin >> fp rounding
        unsigned rowflat = (unsigned)(base + r) * N_CLS + (unsigned)h;
        #pragma unroll
        for (int m = 0; m < 41; ++m) {             // COMPILE-TIME v[] index only
            float e = v[m];
            if ((m + h) != 0 && e > eth) {         // skip background (h=0,m=0)
                float p = e / s;                   // identical division
                if (p > SCORE_TH) {
                    unsigned fb = __float_as_uint(p);
                    atomicAdd(&fhist[(fb >> 9) - FH_BASE], 1u);   // fire-and-forget
                    u64 key = ((u64)fb << 32) | (u64)(0xFFFFFFu - (rowflat + 2u * (unsigned)m));
                    unsigned pos = atomicAdd(&lcnt, 1u);
                    if (pos < CBUF_CAP) cbuf[pos] = key;
                    else { unsigned gp = atomicAdd(cnt, 1u); if (gp < LISTCAP) sel[gp] = key; }
                }
            }
        }
    }
    __syncthreads();
    unsigned total = lcnt; if (total > CBUF_CAP) total = CBUF_CAP;
    if (tid == 0) gbase = atomicAdd(cnt, total);
    __syncthreads();
    unsigned gb = gbase;
    for (unsigned i = tid; i < total; i += 256) {
        unsigned gp = gb + i;
        if (gp < LISTCAP) sel[gp] = cbuf[i];
    }
    __threadfence();
    __syncthreads();
    if (tid == 0) tkt = atomicAdd(tick, 1u);
    __syncthreads();
    if (tkt != gridDim.x - 1) return;

    // ---- winner block: suffix-scan 73728-bin fine hist -> exact tb ----
    unsigned csum = 0;
    for (int k = 0; k < 288; ++k)
        csum += agent_load_u32(&fhist[tid * 288 + k]);
    scs[tid] = csum; ssfx[tid] = csum;
    if (tid == 0) wg = -1;
    __syncthreads();
    #pragma unroll
    for (int off = 1; off < 256; off <<= 1) {
        unsigned a = (tid + off < 256) ? ssfx[tid + off] : 0u;
        __syncthreads();
        ssfx[tid] += a;
        __syncthreads();
    }
    unsigned incl = ssfx[tid], excl = incl - scs[tid];
    if (excl < TOPK && incl >= TOPK) { wg = tid; wex = excl; }
    __syncthreads();
    if (tid == 0) {
        unsigned tb = 0;
        if (wg >= 0) {                             // total >= TOPK
            unsigned cum = wex;
            int gbin = wg * 288;
            for (int i = gbin + 287; i >= gbin; --i) {
                unsigned cc = agent_load_u32(&fhist[i]);
                if (cum + cc >= TOPK) { tb = ((unsigned)i + FH_BASE) << 9; break; }
                cum += cc;
            }
        }
        *ptb = tb;                                 // tb==0 -> keep everything
    }
}

// ------- K2: compact keys >= tb, then winner block ranks+decodes top-K -------
// Rank r = #{keys > my} over the S selected (distinct) keys: bijection onto
// [0,S). Winner decodes its keys straight into rank slots; fills defaults.
__global__ __launch_bounds__(256) void k_select_rank(
        const u64* __restrict__ sel, const unsigned* __restrict__ cnt,
        const unsigned* __restrict__ ptb,
        u64* __restrict__ sel2, unsigned* __restrict__ cnt2,
        unsigned* __restrict__ tick, const float* __restrict__ boxes,
        float* __restrict__ boxK, float* __restrict__ scoreK, int* __restrict__ clsK) {
    __shared__ u64 ch[2048];
    __shared__ unsigned tkt;
    int tid = threadIdx.x, ln = tid & 63;
    unsigned tb = *ptb;
    unsigned M = *cnt; if (M > LISTCAP) M = LISTCAP;
    unsigned stride = gridDim.x * blockDim.x;
    for (unsigned ibase = blockIdx.x * blockDim.x; ibase < M; ibase += stride) {
        unsigned i = ibase + tid;
        bool act = (i < M);
        u64 key = act ? sel[i] : 0ull;
        bool c = act && ((unsigned)(key >> 32) >= tb);
        u64 b = __ballot(c);
        int n = __popcll(b);
        if (n) {
            unsigned wb = 0;
            if (ln == 0) wb = atomicAdd(cnt2, (unsigned)n);
            wb = __shfl(wb, 0);
            if (c) {
                unsigned pos = wb + (unsigned)__popcll(b & ((1ull << ln) - 1ull));
                if (pos < CAP2) agent_store_u64(&sel2[pos], key);  // same-kernel visible
            }
        }
    }
    __threadfence();
    __syncthreads();
    if (tid == 0) tkt = atomicAdd(tick, 1u);
    __syncthreads();
    if (tkt != gridDim.x - 1) return;

    // ---- winner: rank by counting (LDS-tiled) + decode ----
    unsigned S = agent_load_u32(cnt2); if (S > CAP2) S = CAP2;
    for (unsigned s0 = 0; s0 < S; s0 += 256) {
        unsigned t2 = s0 + tid;
        u64 my = (t2 < S) ? agent_load_u64(&sel2[t2]) : 0ull;
        int r = 0;
        for (unsigned c0 = 0; c0 < S; c0 += 2048) {
            unsigned n = S - c0; if (n > 2048) n = 2048;
            __syncthreads();
            for (unsigned i = tid; i < n; i += 256) ch[i] = agent_load_u64(&sel2[c0 + i]);
            __syncthreads();
            if (t2 < S)
                for (unsigned j = 0; j < n; j++) r += (ch[j] > my) ? 1 : 0;
        }
        if (t2 < S && r < TOPK) {
            float sc = __uint_as_float((unsigned)(my >> 32));
            unsigned fi = 0xFFFFFFu - (unsigned)(my & 0xFFFFFFFFull);
            unsigned prop = fi / N_CLS;
            int cls = (int)(fi - prop * N_CLS);
            const float* bx = boxes + (size_t)prop * 4;
            boxK[r * 4 + 0] = fminf(fmaxf(bx[0], 0.0f), IMG_W - 1.0f);
            boxK[r * 4 + 1] = fminf(fmaxf(bx[1], 0.0f), IMG_H - 1.0f);
            boxK[r * 4 + 2] = fminf(fmaxf(bx[2], 0.0f), IMG_W - 1.0f);
            boxK[r * 4 + 3] = fminf(fmaxf(bx[3], 0.0f), IMG_H - 1.0f);
            scoreK[r] = sc;
            clsK[r] = cls;
        }
    }
    for (unsigned t2 = S + tid; t2 < TOPK; t2 += 256) {   // ranks cover [0,S) exactly
        boxK[t2 * 4 + 0] = 0.0f; boxK[t2 * 4 + 1] = 0.0f;
        boxK[t2 * 4 + 2] = 0.0f; boxK[t2 * 4 + 3] = 0.0f;
        scoreK[t2] = 0.0f; clsK[t2] = -1;
    }
}

// ------- K3: conflict bit-matrix, then winner block runs Jacobi NMS + output -------
__global__ __launch_bounds__(1024) void k_conflict_nms(
        const float* __restrict__ boxK, const int* __restrict__ clsK,
        const float* __restrict__ scoreK, u64* __restrict__ mask,
        unsigned* __restrict__ tick, float* __restrict__ out) {
    __shared__ u64 words[16];
    __shared__ int changed;
    __shared__ unsigned tkt;
    int tid = threadIdx.x;
    int t = blockIdx.x * 1024 + tid;
    if (t < TOPK * 16) {
        int i = t >> 4, w = t & 15;
        const float4* b4 = (const float4*)boxK;
        float4 bi = b4[i];
        int ci = clsK[i];
        float ai = (bi.z - bi.x) * (bi.w - bi.y);
        u64 m = 0;
        int jbase = w << 6;
        for (int jj = 0; jj < 64; jj++) {
            int j = jbase + jj;
            if (j >= TOPK) break;
            float4 bj = b4[j];
            float aj = (bj.z - bj.x) * (bj.w - bj.y);
            float ww = fmaxf(fminf(bi.z, bj.z) - fmaxf(bi.x, bj.x), 0.0f);
            float hh = fmaxf(fminf(bi.w, bj.w) - fmaxf(bi.y, bj.y), 0.0f);
            float inter = ww * hh;
            float iou = inter / (ai + aj - inter + 1e-9f);
            if (iou > 0.5f && ci == clsK[j]) m |= (1ull << jj);
        }
        agent_store_u64(&mask[(size_t)i * 16 + w], m);    // same-kernel visible
    }
    __threadfence();
    __syncthreads();
    if (tid == 0) tkt = atomicAdd(tick, 1u);
    __syncthreads();
    if (tkt != gridDim.x - 1) return;

    // ---- winner (1024 threads): Jacobi fixed-point of greedy NMS ----
    int wv = tid >> 6, ln = tid & 63;
    bool valid = (tid < TOPK) && (scoreK[tid] > 0.0f);
    u64 row[16];
    #pragma unroll
    for (int w = 0; w < 16; w++)
        row[w] = (tid < TOPK) ? agent_load_u64(&mask[(size_t)tid * 16 + w]) : 0ull;
    u64 lowmask = (1ull << ln) - 1ull;
    bool keep = valid;
    for (int it = 0; it < 1024; ++it) {
        u64 b = __ballot(keep);
        if (ln == 0) words[wv] = b;
        if (tid == 0) changed = 0;
        __syncthreads();
        u64 sup = 0;
        for (int w = 0; w <= wv; w++) {          // wv is wave-uniform
            u64 kw = words[w];
            if (w == wv) kw &= lowmask;
            sup |= row[w] & kw;
        }
        bool nk = valid && (sup == 0ull);
        if (nk != keep) changed = 1;
        keep = nk;
        __syncthreads();
        if (!changed) break;
    }
    if (tid < TOPK) {
        float x1 = boxK[tid * 4 + 0], y1 = boxK[tid * 4 + 1];
        float x2 = boxK[tid * 4 + 2], y2 = boxK[tid * 4 + 3];
        float sc = scoreK[tid];
        out[tid * 5 + 0] = keep ? x1 : 0.0f;
        out[tid * 5 + 1] = keep ? y1 : 0.0f;
        out[tid * 5 + 2] = keep ? x2 : 0.0f;
        out[tid * 5 + 3] = keep ? y2 : 0.0f;
        out[tid * 5 + 4] = keep ? sc : 0.0f;
    }
}

extern "C" void kernel_launch(void* const* d_in, const int* in_sizes, int n_in,
                              void* d_out, int out_size, void* d_ws, size_t ws_size,
                              hipStream_t stream) {
    const float* logits = (const float*)d_in[0];
    const float* boxes  = (const float*)d_in[1];
    float* out = (float*)d_out;
    int nrows = in_sizes[0] / N_CLS;   // 200000

    char* w = (char*)d_ws;
    unsigned* cnt    = (unsigned*)(w + OFF_CNT);
    unsigned* cnt2   = (unsigned*)(w + OFF_CNT2);
    unsigned* tick1  = (unsigned*)(w + OFF_TICK1);
    unsigned* tick2  = (unsigned*)(w + OFF_TICK2);
    unsigned* tick3  = (unsigned*)(w + OFF_TICK3);
    unsigned* ptb    = (unsigned*)(w + OFF_TB);
    unsigned* fhist  = (unsigned*)(w + OFF_FH);
    u64* sel         = (u64*)(w + OFF_SEL);
    u64* sel2        = (u64*)(w + OFF_SEL2);
    float* boxK      = (float*)(w + OFF_BOX);
    float* scoreK    = (float*)(w + OFF_SCORE);
    int* clsK        = (int*)(w + OFF_CLS);
    u64* mask        = (u64*)(w + OFF_MASK);

    hipMemsetAsync(w, 0, MEMSET_BYTES, stream);

    int nblk = (nrows + ROWS_PER_BLK - 1) / ROWS_PER_BLK;   // 1563
    k_pass1<<<nblk, 256, 0, stream>>>(logits, nrows, sel, cnt, fhist, tick1, ptb);
    k_select_rank<<<1024, 256, 0, stream>>>(sel, cnt, ptb, sel2, cnt2, tick2,
                                            boxes, boxK, scoreK, clsK);
    k_conflict_nms<<<16, 1024, 0, stream>>>(boxK, clsK, scoreK, mask, tick3, out);
}

// Round 7
// 394.400 us; speedup vs baseline: 1.6381x; 1.6381x over previous
//
#include <hip/hip_runtime.h>
#include <stdint.h>
#include <math.h>

#define N_CLS    81
#define TOPK     1000
#define LISTCAP  (1u << 21)     // 2M candidate keys (16 MB)
#define CAP2     16384          // final selection capacity
#define RANKCAP  4096           // bitonic sort capacity (LDS, 32 KB)
#define SCORE_TH 0.05f
#define IMG_W    1333.0f
#define IMG_H    800.0f
#define GH_REP   8              // coarse-hist replicas (atomic spread)

// coarse bucket = float_bits >> 19, range for (0.05, 1.0] is [1961, 2032]
#define GH_BASE  1905           // ghist index = (bits>>19) - GH_BASE, in [56,127]

// workspace layout (byte offsets)
#define OFF_CNT    0                       // u32 total candidates
#define OFF_CNT2   8                       // u32 selected count
#define OFF_TICK1  16                      // u32 K1 done-ticket
#define OFF_TICK2  20                      // u32 K2 done-ticket
#define OFF_TICK3  24                      // u32 K3 done-ticket
#define OFF_TICK4  28                      // u32 K4 done-ticket
#define OFF_SB     32                      // i32 coarse bucket B (-1 if < TOPK total)
#define OFF_CA     36                      // u32 count strictly above bucket B
#define OFF_TB     40                      // u32 exact threshold bits
#define OFF_GH     64                      // u32[GH_REP][128] coarse hist (4096 B)
#define OFF_RH     4608                    // u32[1024] refined hist (4096 B)
#define MEMSET_BYTES 8704
#define OFF_SEL    16768                   // u64[LISTCAP]
#define OFF_SEL2   16793984                // u64[CAP2]
#define OFF_BOX    16925056                // f32[1000*4]
#define OFF_SCORE  16941056                // f32[1000]
#define OFF_CLS    16945056                // i32[1000]
#define OFF_MASK   16949056                // u64[1000*16] conflict bit matrix

#define ROWS_PER_BLK 128
#define TILE_FLOATS  (ROWS_PER_BLK * N_CLS)   // 10368 floats = 41472 B (16B-aligned)
#define CBUF_CAP     1024

typedef unsigned long long u64;

// direct global->LDS 16B DMA (m97 pattern): LDS dest = wave-uniform base + lane*16
__device__ __forceinline__ void gload_lds16(const float* g, float* l) {
    __builtin_amdgcn_global_load_lds(
        (const __attribute__((address_space(1))) unsigned int*)g,
        (__attribute__((address_space(3))) unsigned int*)l, 16, 0, 0);
}

__device__ __forceinline__ unsigned agent_load_u32(const unsigned* p) {
    return __hip_atomic_load(p, __ATOMIC_RELAXED, __HIP_MEMORY_SCOPE_AGENT);
}
__device__ __forceinline__ u64 agent_load_u64(const u64* p) {
    return __hip_atomic_load(p, __ATOMIC_RELAXED, __HIP_MEMORY_SCOPE_AGENT);
}
__device__ __forceinline__ void agent_store_u64(u64* p, u64 v) {
    __hip_atomic_store(p, v, __ATOMIC_RELAXED, __HIP_MEMORY_SCOPE_AGENT);
}

__device__ __forceinline__ void decode_slot(
        int r, u64 key, const float* __restrict__ boxes,
        float* __restrict__ boxK, float* __restrict__ scoreK, int* __restrict__ clsK) {
    if (key != 0ull) {
        float sc = __uint_as_float((unsigned)(key >> 32));
        unsigned fi = 0xFFFFFFu - (unsigned)(key & 0xFFFFFFFFull);
        unsigned prop = fi / N_CLS;
        int cls = (int)(fi - prop * N_CLS);
        const float* bx = boxes + (size_t)prop * 4;
        boxK[r * 4 + 0] = fminf(fmaxf(bx[0], 0.0f), IMG_W - 1.0f);
        boxK[r * 4 + 1] = fminf(fmaxf(bx[1], 0.0f), IMG_H - 1.0f);
        boxK[r * 4 + 2] = fminf(fmaxf(bx[2], 0.0f), IMG_W - 1.0f);
        boxK[r * 4 + 3] = fminf(fmaxf(bx[3], 0.0f), IMG_H - 1.0f);
        scoreK[r] = sc;
        clsK[r] = cls;
    } else {
        boxK[r * 4 + 0] = 0.0f; boxK[r * 4 + 1] = 0.0f;
        boxK[r * 4 + 2] = 0.0f; boxK[r * 4 + 3] = 0.0f;
        scoreK[r] = 0.0f; clsK[r] = -1;
    }
}

// ------- K1: round-2 pass1 VERBATIM (proven 52us) + ticket + coarse-B scan -------
// 128-row LDS tile via global_load_lds, 256 threads, pair-of-threads per row.
// Per-row math is the verified bit-exact form (class-parity pair split, bitrev5
// stack tree, shfl_xor(1) for max and top-level sum association). Histogram is
// the round-2 LDS lh[128] -> replicated ghist (NOT per-candidate global atomics:
// round-6's fhist atomics regressed pass1). Winner block: parallel suffix scan
// of the 128 coarse bins -> B, c_above.
__global__ __launch_bounds__(256) void k_pass1(
        const float* __restrict__ logits, int nrows,
        u64* __restrict__ sel, unsigned* __restrict__ cnt,
        unsigned* __restrict__ ghist, unsigned* __restrict__ tick,
        int* __restrict__ psB, unsigned* __restrict__ pCA) {
    __shared__ float tile[TILE_FLOATS];
    __shared__ unsigned lh[128];
    __shared__ u64 cbuf[CBUF_CAP];
    __shared__ unsigned lcnt, gbase, tkt, wCA;
    __shared__ int wB;
    int tid = threadIdx.x, wv = tid >> 6, ln = tid & 63;
    for (int i = tid; i < 128; i += 256) lh[i] = 0;
    if (tid == 0) lcnt = 0;

    int base = blockIdx.x * ROWS_PER_BLK;
    int nr = nrows - base; if (nr > ROWS_PER_BLK) nr = ROWS_PER_BLK;
    const float* gtile = logits + (size_t)base * N_CLS;

    if (nr == ROWS_PER_BLK) {
        // 10 iterations x 4 waves x 1KB = 40960 B coalesced direct-to-LDS
        #pragma unroll
        for (int it = 0; it < 10; ++it) {
            int c = it * 1024 + wv * 256;          // float offset, wave-uniform
            gload_lds16(gtile + c + ln * 4, tile + c);
        }
        if (tid < TILE_FLOATS - 10240) tile[10240 + tid] = gtile[10240 + tid];
    } else {
        for (int i = tid; i < nr * N_CLS; i += 256) tile[i] = gtile[i];
    }
    __syncthreads();   // drains vmcnt (global_load_lds) + lgkmcnt

    int r = tid >> 1, h = tid & 1;
    if (r < nr) {
        const int rb = r * N_CLS + h;              // first owned class in LDS
        float v[41];
        #pragma unroll
        for (int m = 0; m < 40; ++m) v[m] = tile[rb + 2 * m];
        v[40] = (h == 0) ? tile[rb + 80] : 0.0f;   // class 80 only exists for h=0

        // ---- row max (exact, order-free) ----
        float mx = v[0];
        #pragma unroll
        for (int m = 1; m < 40; ++m) mx = fmaxf(mx, v[m]);
        mx = fmaxf(mx, (h == 0) ? v[40] : v[0]);
        float om = __shfl_xor(mx, 1);
        float mrow = fmaxf(mx, om);

        // ---- exps (op-identical to reference kernel) ----
        #pragma unroll
        for (int m = 0; m < 40; ++m) v[m] = expf(v[m] - mrow);
        v[40] = (h == 0) ? expf(v[40] - mrow) : 0.0f;

        // ---- per-thread bitrev subtree over leaves l = h + 2*b ----
        float stk0 = 0.f, stk1 = 0.f, stk2 = 0.f, stk3 = 0.f, stk4 = 0.f;
        float S = 0.f;
        #pragma unroll
        for (int i = 0; i < 32; ++i) {
            const int b = ((i & 1) << 4) | ((i & 2) << 2) | (i & 4) |
                          ((i & 8) >> 2) | ((i & 16) >> 4);   // bitrev5(i)
            float x = v[b];
            if (b < 8) x += v[b + 32];
            else if (b == 8) x = (h == 0) ? x + v[40] : x;
            if (i & 1) { x = stk0 + x;
              if (i & 2) { x = stk1 + x;
                if (i & 4) { x = stk2 + x;
                  if (i & 8) { x = stk3 + x;
                    if (i & 16) { S = stk4 + x; } else stk4 = x;
                  } else stk3 = x;
                } else stk2 = x;
              } else stk1 = x;
            } else stk0 = x;
        }
        float oS = __shfl_xor(S, 1);
        float s = (h == 0) ? (S + oS) : (oS + S);  // exact top-level association

        // ---- emit: conservative pre-filter, then bit-exact p>0.05 ----
        float eth = 0.0499f * s;                   // 0.2% margin >> fp rounding
        unsigned rowflat = (unsigned)(base + r) * N_CLS + (unsigned)h;
        #pragma unroll
        for (int m = 0; m < 41; ++m) {             // COMPILE-TIME v[] index only
            float e = v[m];
            if ((m + h) != 0 && e > eth) {         // skip background (h=0,m=0)
                float p = e / s;                   // identical division
                if (p > SCORE_TH) {
                    unsigned fb = __float_as_uint(p);
                    atomicAdd(&lh[(fb >> 19) - GH_BASE], 1u);
                    u64 key = ((u64)fb << 32) | (u64)(0xFFFFFFu - (rowflat + 2u * (unsigned)m));
                    unsigned pos = atomicAdd(&lcnt, 1u);
                    if (pos < CBUF_CAP) cbuf[pos] = key;
                    else { unsigned gp = atomicAdd(cnt, 1u); if (gp < LISTCAP) sel[gp] = key; }
                }
            }
        }
    }
    __syncthreads();
    unsigned* gh = ghist + (blockIdx.x & (GH_REP - 1)) * 128;
    for (int i = tid; i < 128; i += 256) {
        unsigned vv = lh[i];
        if (vv) atomicAdd(&gh[i], vv);
    }
    unsigned total = lcnt; if (total > CBUF_CAP) total = CBUF_CAP;
    if (tid == 0) gbase = atomicAdd(cnt, total);
    __syncthreads();
    unsigned gb = gbase;
    for (unsigned i = tid; i < total; i += 256) {
        unsigned gp = gb + i;
        if (gp < LISTCAP) sel[gp] = cbuf[i];
    }
    __threadfence();
    __syncthreads();
    if (tid == 0) tkt = atomicAdd(tick, 1u);
    __syncthreads();
    if (tkt != gridDim.x - 1) return;

    // ---- winner block: parallel coarse suffix-scan (tile LDS reused) ----
    unsigned* scs = (unsigned*)tile;               // [128]
    unsigned* sfx = scs + 128;                     // [128]
    if (tid < 128) {
        unsigned c = 0;
        #pragma unroll
        for (int rr = 0; rr < GH_REP; ++rr)
            c += agent_load_u32(&ghist[rr * 128 + tid]);
        scs[tid] = c; sfx[tid] = c;
    }
    if (tid == 0) wB = -1;
    __syncthreads();
    #pragma unroll
    for (int off = 1; off < 128; off <<= 1) {
        unsigned a = 0;
        if (tid < 128) a = (tid + off < 128) ? sfx[tid + off] : 0u;
        __syncthreads();
        if (tid < 128) sfx[tid] += a;
        __syncthreads();
    }
    if (tid == 0) wCA = sfx[0];                    // total (B<0 fallback)
    __syncthreads();
    if (tid < 128) {
        unsigned incl = sfx[tid], excl = incl - scs[tid];
        if (excl < TOPK && incl >= TOPK) { wB = tid; wCA = excl; }
    }
    __syncthreads();
    if (tid == 0) { *psB = wB; *pCA = wCA; }
}

// ------- K2: refined 1024-bin hist inside bucket B; winner computes exact tb -------
__global__ __launch_bounds__(256) void k_refine(
        const u64* __restrict__ sel, const unsigned* __restrict__ cnt,
        unsigned* __restrict__ rhist, unsigned* __restrict__ tick,
        const int* __restrict__ psB, const unsigned* __restrict__ pCA,
        unsigned* __restrict__ ptb) {
    __shared__ unsigned lh[1024];
    __shared__ unsigned rbin[1024];
    __shared__ unsigned sgrp[256], ssfx[256];
    __shared__ int wg;
    __shared__ unsigned wcab, tkt;
    int tid = threadIdx.x;
    int B = *psB;
    if (B >= 0) {
        for (int i = tid; i < 1024; i += 256) lh[i] = 0;
        __syncthreads();
        unsigned Bbits = (unsigned)(B + GH_BASE);
        unsigned M = *cnt; if (M > LISTCAP) M = LISTCAP;
        unsigned stride = gridDim.x * blockDim.x;
        for (unsigned i = blockIdx.x * blockDim.x + tid; i < M; i += stride) {
            unsigned bv = (unsigned)(sel[i] >> 32);
            if ((bv >> 19) == Bbits) atomicAdd(&lh[(bv >> 9) & 1023u], 1u);
        }
        __syncthreads();
        for (int i = tid; i < 1024; i += 256) {
            unsigned vv = lh[i];
            if (vv) atomicAdd(&rhist[i], vv);
        }
    }
    __threadfence();
    __syncthreads();
    if (tid == 0) tkt = atomicAdd(tick, 1u);
    __syncthreads();
    if (tkt != gridDim.x - 1) return;

    // ---- winner: parallel exact-threshold find ----
    if (B < 0) { if (tid == 0) *ptb = 0u; return; }
    unsigned CA = *pCA;
    unsigned gsum = 0;
    #pragma unroll
    for (int k = 0; k < 4; ++k) {
        unsigned bv = agent_load_u32(&rhist[tid * 4 + k]);
        rbin[tid * 4 + k] = bv; gsum += bv;
    }
    sgrp[tid] = gsum; ssfx[tid] = gsum;
    if (tid == 0) wg = -1;
    __syncthreads();
    #pragma unroll
    for (int off = 1; off < 256; off <<= 1) {
        unsigned a = (tid + off < 256) ? ssfx[tid + off] : 0u;
        __syncthreads();
        ssfx[tid] += a;
        __syncthreads();
    }
    unsigned incl = ssfx[tid], excl = incl - sgrp[tid];
    if (CA + excl < TOPK && CA + incl >= TOPK) { wg = tid; wcab = CA + excl; }
    __syncthreads();
    if (tid == 0) {
        int g = wg; unsigned sb = 0;
        if (g >= 0) {
            unsigned cab = wcab;
            for (int i = g * 4 + 3; i >= g * 4; --i) {
                unsigned cc = rbin[i];
                if (cab + cc >= TOPK) { sb = (unsigned)i; break; }
                cab += cc;
            }
        }
        *ptb = ((unsigned)(B + GH_BASE) << 19) | (sb << 9);
    }
}

// ------- K3: compact keys >= tb; winner block BITONIC-sorts + decodes -------
// Bitonic sort of S (~1030) distinct u64 keys in 32 KB LDS with 1024 threads:
// 78 fully-parallel stages (~2 CE/thread each) replaces round-6's 287us
// single-block latency-chain counting rank. Sorted position == rank (distinct
// keys, order-independent -> deterministic). Counting fallback for S>RANKCAP
// (unreachable: threshold bin is 512 ULP wide, ~tens of keys).
__global__ __launch_bounds__(1024) void k_select_rank(
        const u64* __restrict__ sel, const unsigned* __restrict__ cnt,
        const unsigned* __restrict__ ptb,
        u64* __restrict__ sel2, unsigned* __restrict__ cnt2,
        unsigned* __restrict__ tick, const float* __restrict__ boxes,
        float* __restrict__ boxK, float* __restrict__ scoreK, int* __restrict__ clsK) {
    __shared__ u64 ch[RANKCAP];                    // 32 KB
    __shared__ unsigned tkt;
    int tid = threadIdx.x, ln = tid & 63;
    unsigned tb = *ptb;
    unsigned M = *cnt; if (M > LISTCAP) M = LISTCAP;
    unsigned stride = gridDim.x * blockDim.x;
    for (unsigned ibase = blockIdx.x * blockDim.x; ibase < M; ibase += stride) {
        unsigned i = ibase + tid;
        bool act = (i < M);
        u64 key = act ? sel[i] : 0ull;
        bool c = act && ((unsigned)(key >> 32) >= tb);
        u64 b = __ballot(c);
        int n = __popcll(b);
        if (n) {
            unsigned wb = 0;
            if (ln == 0) wb = atomicAdd(cnt2, (unsigned)n);
            wb = __shfl(wb, 0);
            if (c) {
                unsigned pos = wb + (unsigned)__popcll(b & ((1ull << ln) - 1ull));
                if (pos < CAP2) agent_store_u64(&sel2[pos], key);  // same-kernel visible
            }
        }
    }
    __threadfence();
    __syncthreads();
    if (tid == 0) tkt = atomicAdd(tick, 1u);
    __syncthreads();
    if (tkt != gridDim.x - 1) return;

    unsigned S = agent_load_u32(cnt2); if (S > CAP2) S = CAP2;
    if (S <= RANKCAP) {
        // ---- load + zero-pad ----
        for (unsigned i = tid; i < RANKCAP; i += 1024)
            ch[i] = (i < S) ? agent_load_u64(&sel2[i]) : 0ull;
        __syncthreads();
        // ---- bitonic sort, DESCENDING (zeros sink to the end) ----
        for (unsigned k = 2; k <= RANKCAP; k <<= 1) {
            for (unsigned j = k >> 1; j > 0; j >>= 1) {
                #pragma unroll
                for (unsigned ii = 0; ii < RANKCAP / 1024; ++ii) {
                    unsigned i = ii * 1024 + tid;
                    unsigned ixj = i ^ j;
                    if (ixj > i) {
                        u64 a = ch[i], b = ch[ixj];
                        bool sw = ((i & k) == 0) ? (a < b) : (a > b);
                        if (sw) { ch[i] = b; ch[ixj] = a; }
                    }
                }
                __syncthreads();
            }
        }
        // ---- decode rank slots [0, TOPK) ----
        for (unsigned r = tid; r < TOPK; r += 1024)
            decode_slot((int)r, ch[r], boxes, boxK, scoreK, clsK);
    } else {
        // ---- fallback: parallel counting rank (practically unreachable) ----
        for (unsigned s0 = 0; s0 < S; s0 += 1024) {
            unsigned t2 = s0 + tid;
            u64 my = (t2 < S) ? agent_load_u64(&sel2[t2]) : 0ull;
            int r = 0;
            for (unsigned c0 = 0; c0 < S; c0 += RANKCAP) {
                unsigned n = S - c0; if (n > RANKCAP) n = RANKCAP;
                __syncthreads();
                for (unsigned i = tid; i < n; i += 1024)
                    ch[i] = agent_load_u64(&sel2[c0 + i]);
                __syncthreads();
                if (t2 < S)
                    for (unsigned jj = 0; jj < n; jj++) r += (ch[jj] > my) ? 1 : 0;
            }
            if (t2 < S && r < TOPK) decode_slot(r, my, boxes, boxK, scoreK, clsK);
        }
        for (unsigned t2 = S + tid; t2 < TOPK; t2 += 1024)
            decode_slot((int)t2, 0ull, boxes, boxK, scoreK, clsK);
    }
}

// ------- K4: conflict bit-matrix, then winner block runs Jacobi NMS + output -------
__global__ __launch_bounds__(1024) void k_conflict_nms(
        const float* __restrict__ boxK, const int* __restrict__ clsK,
        const float* __restrict__ scoreK, u64* __restrict__ mask,
        unsigned* __restrict__ tick, float* __restrict__ out) {
    __shared__ u64 words[16];
    __shared__ int changed;
    __shared__ unsigned tkt;
    int tid = threadIdx.x;
    int t = blockIdx.x * 1024 + tid;
    if (t < TOPK * 16) {
        int i = t >> 4, w = t & 15;
        const float4* b4 = (const float4*)boxK;
        float4 bi = b4[i];
        int ci = clsK[i];
        float ai = (bi.z - bi.x) * (bi.w - bi.y);
        u64 m = 0;
        int jbase = w << 6;
        for (int jj = 0; jj < 64; jj++) {
            int j = jbase + jj;
            if (j >= TOPK) break;
            float4 bj = b4[j];
            float aj = (bj.z - bj.x) * (bj.w - bj.y);
            float ww = fmaxf(fminf(bi.z, bj.z) - fmaxf(bi.x, bj.x), 0.0f);
            float hh = fmaxf(fminf(bi.w, bj.w) - fmaxf(bi.y, bj.y), 0.0f);
            float inter = ww * hh;
            float iou = inter / (ai + aj - inter + 1e-9f);
            if (iou > 0.5f && ci == clsK[j]) m |= (1ull << jj);
        }
        agent_store_u64(&mask[(size_t)i * 16 + w], m);    // same-kernel visible
    }
    __threadfence();
    __syncthreads();
    if (tid == 0) tkt = atomicAdd(tick, 1u);
    __syncthreads();
    if (tkt != gridDim.x - 1) return;

    // ---- winner (1024 threads): Jacobi fixed-point of greedy NMS ----
    int wv = tid >> 6, ln = tid & 63;
    bool valid = (tid < TOPK) && (scoreK[tid] > 0.0f);
    u64 row[16];
    #pragma unroll
    for (int w = 0; w < 16; w++)
        row[w] = (tid < TOPK) ? agent_load_u64(&mask[(size_t)tid * 16 + w]) : 0ull;
    u64 lowmask = (1ull << ln) - 1ull;
    bool keep = valid;
    for (int it = 0; it < 1024; ++it) {
        u64 b = __ballot(keep);
        if (ln == 0) words[wv] = b;
        if (tid == 0) changed = 0;
        __syncthreads();
        u64 sup = 0;
        for (int w = 0; w <= wv; w++) {          // wv is wave-uniform
            u64 kw = words[w];
            if (w == wv) kw &= lowmask;
            sup |= row[w] & kw;
        }
        bool nk = valid && (sup == 0ull);
        if (nk != keep) changed = 1;
        keep = nk;
        __syncthreads();
        if (!changed) break;
    }
    if (tid < TOPK) {
        float x1 = boxK[tid * 4 + 0], y1 = boxK[tid * 4 + 1];
        float x2 = boxK[tid * 4 + 2], y2 = boxK[tid * 4 + 3];
        float sc = scoreK[tid];
        out[tid * 5 + 0] = keep ? x1 : 0.0f;
        out[tid * 5 + 1] = keep ? y1 : 0.0f;
        out[tid * 5 + 2] = keep ? x2 : 0.0f;
        out[tid * 5 + 3] = keep ? y2 : 0.0f;
        out[tid * 5 + 4] = keep ? sc : 0.0f;
    }
}

extern "C" void kernel_launch(void* const* d_in, const int* in_sizes, int n_in,
                              void* d_out, int out_size, void* d_ws, size_t ws_size,
                              hipStream_t stream) {
    const float* logits = (const float*)d_in[0];
    const float* boxes  = (const float*)d_in[1];
    float* out = (float*)d_out;
    int nrows = in_sizes[0] / N_CLS;   // 200000

    char* w = (char*)d_ws;
    unsigned* cnt    = (unsigned*)(w + OFF_CNT);
    unsigned* cnt2   = (unsigned*)(w + OFF_CNT2);
    unsigned* tick1  = (unsigned*)(w + OFF_TICK1);
    unsigned* tick2  = (unsigned*)(w + OFF_TICK2);
    unsigned* tick3  = (unsigned*)(w + OFF_TICK3);
    unsigned* tick4  = (unsigned*)(w + OFF_TICK4);
    int*      psB    = (int*)(w + OFF_SB);
    unsigned* pCA    = (unsigned*)(w + OFF_CA);
    unsigned* ptb    = (unsigned*)(w + OFF_TB);
    unsigned* ghist  = (unsigned*)(w + OFF_GH);
    unsigned* rhist  = (unsigned*)(w + OFF_RH);
    u64* sel         = (u64*)(w + OFF_SEL);
    u64* sel2        = (u64*)(w + OFF_SEL2);
    float* boxK      = (float*)(w + OFF_BOX);
    float* scoreK    = (float*)(w + OFF_SCORE);
    int* clsK        = (int*)(w + OFF_CLS);
    u64* mask        = (u64*)(w + OFF_MASK);

    hipMemsetAsync(w, 0, MEMSET_BYTES, stream);

    int nblk = (nrows + ROWS_PER_BLK - 1) / ROWS_PER_BLK;   // 1563
    k_pass1<<<nblk, 256, 0, stream>>>(logits, nrows, sel, cnt, ghist, tick1, psB, pCA);
    k_refine<<<256, 256, 0, stream>>>(sel, cnt, rhist, tick2, psB, pCA, ptb);
    k_select_rank<<<128, 1024, 0, stream>>>(sel, cnt, ptb, sel2, cnt2, tick3,
                                            boxes, boxK, scoreK, clsK);
    k_conflict_nms<<<16, 1024, 0, stream>>>(boxK, clsK, scoreK, mask, tick4, out);
}

// Round 8
// 255.464 us; speedup vs baseline: 2.5290x; 1.5439x over previous
//
#include <hip/hip_runtime.h>
#include <stdint.h>
#include <math.h>

#define N_CLS    81
#define TOPK     1000
#define LISTCAP  (1u << 21)     // 2M candidate keys (16 MB)
#define CAP2     16384          // final selection capacity
#define RANKCAP  4096           // bitonic sort capacity (LDS, 32 KB)
#define SCORE_TH 0.05f
#define IMG_W    1333.0f
#define IMG_H    800.0f
#define GH_REP   8              // coarse-hist replicas (atomic spread)

// coarse bucket = float_bits >> 19, range for (0.05, 1.0] is [1961, 2032]
#define GH_BASE  1905           // ghist index = (bits>>19) - GH_BASE, in [56,127]

// workspace layout (byte offsets)
#define OFF_CNT    0                       // u32 total candidates
#define OFF_CNT2   8                       // u32 selected count
#define OFF_TICK1  16                      // u32 K1 done-ticket
#define OFF_TICK2  20                      // u32 K2 done-ticket
#define OFF_TICK3  24                      // u32 K3 done-ticket
#define OFF_TICK4  28                      // u32 K4 done-ticket
#define OFF_SB     32                      // i32 coarse bucket B (-1 if < TOPK total)
#define OFF_CA     36                      // u32 count strictly above bucket B
#define OFF_TB     40                      // u32 exact threshold bits
#define OFF_GH     64                      // u32[GH_REP][128] coarse hist (4096 B)
#define OFF_RH     4608                    // u32[1024] refined hist (4096 B)
#define MEMSET_BYTES 8704
#define OFF_SEL    16768                   // u64[LISTCAP]
#define OFF_SEL2   16793984                // u64[CAP2]
#define OFF_BOX    16925056                // f32[1000*4]
#define OFF_SCORE  16941056                // f32[1000]
#define OFF_CLS    16945056                // i32[1000]
#define OFF_MASK   16949056                // u64[1000*16] conflict bit matrix

#define ROWS_PER_BLK 128
#define TILE_FLOATS  (ROWS_PER_BLK * N_CLS)   // 10368 floats = 41472 B (16B-aligned)
#define CBUF_CAP     1024

typedef unsigned long long u64;

// direct global->LDS 16B DMA (m97 pattern): LDS dest = wave-uniform base + lane*16
__device__ __forceinline__ void gload_lds16(const float* g, float* l) {
    __builtin_amdgcn_global_load_lds(
        (const __attribute__((address_space(1))) unsigned int*)g,
        (__attribute__((address_space(3))) unsigned int*)l, 16, 0, 0);
}

// Device-scope atomics operate at the device coherence point (cross-XCD
// coherent by themselves, G12/m20). NO __threadfence() anywhere: a device
// fence forces a per-XCD L2 writeback/invalidate on non-coherent-L2 gfx950;
// 1563 blocks x flush poisoned rounds 3/4/5/7 (pass1 52us -> 166-290us).
// Ordering "my atomic RMWs acked before my ticket": __syncthreads() already
// drains vmcnt(0); the explicit s_waitcnt below is documentation.
__device__ __forceinline__ unsigned agent_load_u32(const unsigned* p) {
    return __hip_atomic_load(p, __ATOMIC_RELAXED, __HIP_MEMORY_SCOPE_AGENT);
}
__device__ __forceinline__ u64 agent_load_u64(const u64* p) {
    return __hip_atomic_load(p, __ATOMIC_RELAXED, __HIP_MEMORY_SCOPE_AGENT);
}
__device__ __forceinline__ void agent_store_u64(u64* p, u64 v) {
    __hip_atomic_store(p, v, __ATOMIC_RELAXED, __HIP_MEMORY_SCOPE_AGENT);
}
__device__ __forceinline__ void drain_vm() {
    asm volatile("s_waitcnt vmcnt(0)" ::: "memory");
}

__device__ __forceinline__ void decode_slot(
        int r, u64 key, const float* __restrict__ boxes,
        float* __restrict__ boxK, float* __restrict__ scoreK, int* __restrict__ clsK) {
    if (key != 0ull) {
        float sc = __uint_as_float((unsigned)(key >> 32));
        unsigned fi = 0xFFFFFFu - (unsigned)(key & 0xFFFFFFFFull);
        unsigned prop = fi / N_CLS;
        int cls = (int)(fi - prop * N_CLS);
        const float* bx = boxes + (size_t)prop * 4;
        boxK[r * 4 + 0] = fminf(fmaxf(bx[0], 0.0f), IMG_W - 1.0f);
        boxK[r * 4 + 1] = fminf(fmaxf(bx[1], 0.0f), IMG_H - 1.0f);
        boxK[r * 4 + 2] = fminf(fmaxf(bx[2], 0.0f), IMG_W - 1.0f);
        boxK[r * 4 + 3] = fminf(fmaxf(bx[3], 0.0f), IMG_H - 1.0f);
        scoreK[r] = sc;
        clsK[r] = cls;
    } else {
        boxK[r * 4 + 0] = 0.0f; boxK[r * 4 + 1] = 0.0f;
        boxK[r * 4 + 2] = 0.0f; boxK[r * 4 + 3] = 0.0f;
        scoreK[r] = 0.0f; clsK[r] = -1;
    }
}

// ------- K1: round-2 pass1 VERBATIM (proven 52us) + fence-free ticket -------
__global__ __launch_bounds__(256) void k_pass1(
        const float* __restrict__ logits, int nrows,
        u64* __restrict__ sel, unsigned* __restrict__ cnt,
        unsigned* __restrict__ ghist, unsigned* __restrict__ tick,
        int* __restrict__ psB, unsigned* __restrict__ pCA) {
    __shared__ float tile[TILE_FLOATS];
    __shared__ unsigned lh[128];
    __shared__ u64 cbuf[CBUF_CAP];
    __shared__ unsigned lcnt, gbase, tkt, wCA;
    __shared__ int wB;
    int tid = threadIdx.x, wv = tid >> 6, ln = tid & 63;
    for (int i = tid; i < 128; i += 256) lh[i] = 0;
    if (tid == 0) lcnt = 0;

    int base = blockIdx.x * ROWS_PER_BLK;
    int nr = nrows - base; if (nr > ROWS_PER_BLK) nr = ROWS_PER_BLK;
    const float* gtile = logits + (size_t)base * N_CLS;

    if (nr == ROWS_PER_BLK) {
        // 10 iterations x 4 waves x 1KB = 40960 B coalesced direct-to-LDS
        #pragma unroll
        for (int it = 0; it < 10; ++it) {
            int c = it * 1024 + wv * 256;          // float offset, wave-uniform
            gload_lds16(gtile + c + ln * 4, tile + c);
        }
        if (tid < TILE_FLOATS - 10240) tile[10240 + tid] = gtile[10240 + tid];
    } else {
        for (int i = tid; i < nr * N_CLS; i += 256) tile[i] = gtile[i];
    }
    __syncthreads();   // drains vmcnt (global_load_lds) + lgkmcnt

    int r = tid >> 1, h = tid & 1;
    if (r < nr) {
        const int rb = r * N_CLS + h;              // first owned class in LDS
        float v[41];
        #pragma unroll
        for (int m = 0; m < 40; ++m) v[m] = tile[rb + 2 * m];
        v[40] = (h == 0) ? tile[rb + 80] : 0.0f;   // class 80 only exists for h=0

        // ---- row max (exact, order-free) ----
        float mx = v[0];
        #pragma unroll
        for (int m = 1; m < 40; ++m) mx = fmaxf(mx, v[m]);
        mx = fmaxf(mx, (h == 0) ? v[40] : v[0]);
        float om = __shfl_xor(mx, 1);
        float mrow = fmaxf(mx, om);

        // ---- exps (op-identical to reference kernel) ----
        #pragma unroll
        for (int m = 0; m < 40; ++m) v[m] = expf(v[m] - mrow);
        v[40] = (h == 0) ? expf(v[40] - mrow) : 0.0f;

        // ---- per-thread bitrev subtree over leaves l = h + 2*b ----
        float stk0 = 0.f, stk1 = 0.f, stk2 = 0.f, stk3 = 0.f, stk4 = 0.f;
        float S = 0.f;
        #pragma unroll
        for (int i = 0; i < 32; ++i) {
            const int b = ((i & 1) << 4) | ((i & 2) << 2) | (i & 4) |
                          ((i & 8) >> 2) | ((i & 16) >> 4);   // bitrev5(i)
            float x = v[b];
            if (b < 8) x += v[b + 32];
            else if (b == 8) x = (h == 0) ? x + v[40] : x;
            if (i & 1) { x = stk0 + x;
              if (i & 2) { x = stk1 + x;
                if (i & 4) { x = stk2 + x;
                  if (i & 8) { x = stk3 + x;
                    if (i & 16) { S = stk4 + x; } else stk4 = x;
                  } else stk3 = x;
                } else stk2 = x;
              } else stk1 = x;
            } else stk0 = x;
        }
        float oS = __shfl_xor(S, 1);
        float s = (h == 0) ? (S + oS) : (oS + S);  // exact top-level association

        // ---- emit: conservative pre-filter, then bit-exact p>0.05 ----
        float eth = 0.0499f * s;                   // 0.2% margin >> fp rounding
        unsigned rowflat = (unsigned)(base + r) * N_CLS + (unsigned)h;
        #pragma unroll
        for (int m = 0; m < 41; ++m) {             // COMPILE-TIME v[] index only
            float e = v[m];
            if ((m + h) != 0 && e > eth) {         // skip background (h=0,m=0)
                float p = e / s;                   // identical division
                if (p > SCORE_TH) {
                    unsigned fb = __float_as_uint(p);
                    atomicAdd(&lh[(fb >> 19) - GH_BASE], 1u);
                    u64 key = ((u64)fb << 32) | (u64)(0xFFFFFFu - (rowflat + 2u * (unsigned)m));
                    unsigned pos = atomicAdd(&lcnt, 1u);
                    if (pos < CBUF_CAP) cbuf[pos] = key;
                    else { unsigned gp = atomicAdd(cnt, 1u); if (gp < LISTCAP) sel[gp] = key; }
                }
            }
        }
    }
    __syncthreads();
    unsigned* gh = ghist + (blockIdx.x & (GH_REP - 1)) * 128;
    for (int i = tid; i < 128; i += 256) {
        unsigned vv = lh[i];
        if (vv) atomicAdd(&gh[i], vv);
    }
    unsigned total = lcnt; if (total > CBUF_CAP) total = CBUF_CAP;
    if (tid == 0) gbase = atomicAdd(cnt, total);
    __syncthreads();
    unsigned gb = gbase;
    for (unsigned i = tid; i < total; i += 256) {
        unsigned gp = gb + i;
        if (gp < LISTCAP) sel[gp] = cbuf[i];
    }
    __syncthreads();                               // drains vmcnt: ghist adds acked
    drain_vm();                                    // (documentation; already 0)
    if (tid == 0) tkt = atomicAdd(tick, 1u);       // relaxed, coherence-point RMW
    __syncthreads();
    if (tkt != gridDim.x - 1) return;

    // ---- winner block: parallel coarse suffix-scan (tile LDS reused) ----
    unsigned* scs = (unsigned*)tile;               // [128]
    unsigned* sfx = scs + 128;                     // [128]
    if (tid < 128) {
        unsigned c = 0;
        #pragma unroll
        for (int rr = 0; rr < GH_REP; ++rr)
            c += agent_load_u32(&ghist[rr * 128 + tid]);   // coherent atomic loads
        scs[tid] = c; sfx[tid] = c;
    }
    if (tid == 0) wB = -1;
    __syncthreads();
    #pragma unroll
    for (int off = 1; off < 128; off <<= 1) {
        unsigned a = 0;
        if (tid < 128) a = (tid + off < 128) ? sfx[tid + off] : 0u;
        __syncthreads();
        if (tid < 128) sfx[tid] += a;
        __syncthreads();
    }
    if (tid == 0) wCA = sfx[0];                    // total (B<0 fallback)
    __syncthreads();
    if (tid < 128) {
        unsigned incl = sfx[tid], excl = incl - scs[tid];
        if (excl < TOPK && incl >= TOPK) { wB = tid; wCA = excl; }
    }
    __syncthreads();
    if (tid == 0) { *psB = wB; *pCA = wCA; }
}

// ------- K2: refined 1024-bin hist inside bucket B; winner computes exact tb -------
__global__ __launch_bounds__(256) void k_refine(
        const u64* __restrict__ sel, const unsigned* __restrict__ cnt,
        unsigned* __restrict__ rhist, unsigned* __restrict__ tick,
        const int* __restrict__ psB, const unsigned* __restrict__ pCA,
        unsigned* __restrict__ ptb) {
    __shared__ unsigned lh[1024];
    __shared__ unsigned rbin[1024];
    __shared__ unsigned sgrp[256], ssfx[256];
    __shared__ int wg;
    __shared__ unsigned wcab, tkt;
    int tid = threadIdx.x;
    int B = *psB;
    if (B >= 0) {
        for (int i = tid; i < 1024; i += 256) lh[i] = 0;
        __syncthreads();
        unsigned Bbits = (unsigned)(B + GH_BASE);
        unsigned M = *cnt; if (M > LISTCAP) M = LISTCAP;
        unsigned stride = gridDim.x * blockDim.x;
        for (unsigned i = blockIdx.x * blockDim.x + tid; i < M; i += stride) {
            unsigned bv = (unsigned)(sel[i] >> 32);
            if ((bv >> 19) == Bbits) atomicAdd(&lh[(bv >> 9) & 1023u], 1u);
        }
        __syncthreads();
        for (int i = tid; i < 1024; i += 256) {
            unsigned vv = lh[i];
            if (vv) atomicAdd(&rhist[i], vv);
        }
    }
    __syncthreads();
    drain_vm();
    if (tid == 0) tkt = atomicAdd(tick, 1u);
    __syncthreads();
    if (tkt != gridDim.x - 1) return;

    // ---- winner: parallel exact-threshold find ----
    if (B < 0) { if (tid == 0) *ptb = 0u; return; }
    unsigned CA = *pCA;
    unsigned gsum = 0;
    #pragma unroll
    for (int k = 0; k < 4; ++k) {
        unsigned bv = agent_load_u32(&rhist[tid * 4 + k]);
        rbin[tid * 4 + k] = bv; gsum += bv;
    }
    sgrp[tid] = gsum; ssfx[tid] = gsum;
    if (tid == 0) wg = -1;
    __syncthreads();
    #pragma unroll
    for (int off = 1; off < 256; off <<= 1) {
        unsigned a = (tid + off < 256) ? ssfx[tid + off] : 0u;
        __syncthreads();
        ssfx[tid] += a;
        __syncthreads();
    }
    unsigned incl = ssfx[tid], excl = incl - sgrp[tid];
    if (CA + excl < TOPK && CA + incl >= TOPK) { wg = tid; wcab = CA + excl; }
    __syncthreads();
    if (tid == 0) {
        int g = wg; unsigned sb = 0;
        if (g >= 0) {
            unsigned cab = wcab;
            for (int i = g * 4 + 3; i >= g * 4; --i) {
                unsigned cc = rbin[i];
                if (cab + cc >= TOPK) { sb = (unsigned)i; break; }
                cab += cc;
            }
        }
        *ptb = ((unsigned)(B + GH_BASE) << 19) | (sb << 9);
    }
}

// ------- K3: compact keys >= tb; winner block BITONIC-sorts + decodes -------
__global__ __launch_bounds__(1024) void k_select_rank(
        const u64* __restrict__ sel, const unsigned* __restrict__ cnt,
        const unsigned* __restrict__ ptb,
        u64* __restrict__ sel2, unsigned* __restrict__ cnt2,
        unsigned* __restrict__ tick, const float* __restrict__ boxes,
        float* __restrict__ boxK, float* __restrict__ scoreK, int* __restrict__ clsK) {
    __shared__ u64 ch[RANKCAP];                    // 32 KB
    __shared__ unsigned tkt;
    int tid = threadIdx.x, ln = tid & 63;
    unsigned tb = *ptb;
    unsigned M = *cnt; if (M > LISTCAP) M = LISTCAP;
    unsigned stride = gridDim.x * blockDim.x;
    for (unsigned ibase = blockIdx.x * blockDim.x; ibase < M; ibase += stride) {
        unsigned i = ibase + tid;
        bool act = (i < M);
        u64 key = act ? sel[i] : 0ull;
        bool c = act && ((unsigned)(key >> 32) >= tb);
        u64 b = __ballot(c);
        int n = __popcll(b);
        if (n) {
            unsigned wb = 0;
            if (ln == 0) wb = atomicAdd(cnt2, (unsigned)n);
            wb = __shfl(wb, 0);
            if (c) {
                unsigned pos = wb + (unsigned)__popcll(b & ((1ull << ln) - 1ull));
                if (pos < CAP2) agent_store_u64(&sel2[pos], key);  // coherence-point store
            }
        }
    }
    __syncthreads();
    drain_vm();
    if (tid == 0) tkt = atomicAdd(tick, 1u);
    __syncthreads();
    if (tkt != gridDim.x - 1) return;

    unsigned S = agent_load_u32(cnt2); if (S > CAP2) S = CAP2;
    if (S <= RANKCAP) {
        // ---- load + zero-pad ----
        for (unsigned i = tid; i < RANKCAP; i += 1024)
            ch[i] = (i < S) ? agent_load_u64(&sel2[i]) : 0ull;
        __syncthreads();
        // ---- bitonic sort, DESCENDING (zeros sink to the end) ----
        for (unsigned k = 2; k <= RANKCAP; k <<= 1) {
            for (unsigned j = k >> 1; j > 0; j >>= 1) {
                #pragma unroll
                for (unsigned ii = 0; ii < RANKCAP / 1024; ++ii) {
                    unsigned i = ii * 1024 + tid;
                    unsigned ixj = i ^ j;
                    if (ixj > i) {
                        u64 a = ch[i], b = ch[ixj];
                        bool sw = ((i & k) == 0) ? (a < b) : (a > b);
                        if (sw) { ch[i] = b; ch[ixj] = a; }
                    }
                }
                __syncthreads();
            }
        }
        // ---- decode rank slots [0, TOPK) ----
        for (unsigned r = tid; r < TOPK; r += 1024)
            decode_slot((int)r, ch[r], boxes, boxK, scoreK, clsK);
    } else {
        // ---- fallback: parallel counting rank (practically unreachable) ----
        for (unsigned s0 = 0; s0 < S; s0 += 1024) {
            unsigned t2 = s0 + tid;
            u64 my = (t2 < S) ? agent_load_u64(&sel2[t2]) : 0ull;
            int r = 0;
            for (unsigned c0 = 0; c0 < S; c0 += RANKCAP) {
                unsigned n = S - c0; if (n > RANKCAP) n = RANKCAP;
                __syncthreads();
                for (unsigned i = tid; i < n; i += 1024)
                    ch[i] = agent_load_u64(&sel2[c0 + i]);
                __syncthreads();
                if (t2 < S)
                    for (unsigned jj = 0; jj < n; jj++) r += (ch[jj] > my) ? 1 : 0;
            }
            if (t2 < S && r < TOPK) decode_slot(r, my, boxes, boxK, scoreK, clsK);
        }
        for (unsigned t2 = S + tid; t2 < TOPK; t2 += 1024)
            decode_slot((int)t2, 0ull, boxes, boxK, scoreK, clsK);
    }
}

// ------- K4: conflict bit-matrix, then winner block runs Jacobi NMS + output -------
__global__ __launch_bounds__(1024) void k_conflict_nms(
        const float* __restrict__ boxK, const int* __restrict__ clsK,
        const float* __restrict__ scoreK, u64* __restrict__ mask,
        unsigned* __restrict__ tick, float* __restrict__ out) {
    __shared__ u64 words[16];
    __shared__ int changed;
    __shared__ unsigned tkt;
    int tid = threadIdx.x;
    int t = blockIdx.x * 1024 + tid;
    if (t < TOPK * 16) {
        int i = t >> 4, w = t & 15;
        const float4* b4 = (const float4*)boxK;
        float4 bi = b4[i];
        int ci = clsK[i];
        float ai = (bi.z - bi.x) * (bi.w - bi.y);
        u64 m = 0;
        int jbase = w << 6;
        for (int jj = 0; jj < 64; jj++) {
            int j = jbase + jj;
            if (j >= TOPK) break;
            float4 bj = b4[j];
            float aj = (bj.z - bj.x) * (bj.w - bj.y);
            float ww = fmaxf(fminf(bi.z, bj.z) - fmaxf(bi.x, bj.x), 0.0f);
            float hh = fmaxf(fminf(bi.w, bj.w) - fmaxf(bi.y, bj.y), 0.0f);
            float inter = ww * hh;
            float iou = inter / (ai + aj - inter + 1e-9f);
            if (iou > 0.5f && ci == clsK[j]) m |= (1ull << jj);
        }
        agent_store_u64(&mask[(size_t)i * 16 + w], m);    // coherence-point store
    }
    __syncthreads();
    drain_vm();
    if (tid == 0) tkt = atomicAdd(tick, 1u);
    __syncthreads();
    if (tkt != gridDim.x - 1) return;

    // ---- winner (1024 threads): Jacobi fixed-point of greedy NMS ----
    int wv = tid >> 6, ln = tid & 63;
    bool valid = (tid < TOPK) && (scoreK[tid] > 0.0f);
    u64 row[16];
    #pragma unroll
    for (int w = 0; w < 16; w++)
        row[w] = (tid < TOPK) ? agent_load_u64(&mask[(size_t)tid * 16 + w]) : 0ull;
    u64 lowmask = (1ull << ln) - 1ull;
    bool keep = valid;
    for (int it = 0; it < 1024; ++it) {
        u64 b = __ballot(keep);
        if (ln == 0) words[wv] = b;
        if (tid == 0) changed = 0;
        __syncthreads();
        u64 sup = 0;
        for (int w = 0; w <= wv; w++) {          // wv is wave-uniform
            u64 kw = words[w];
            if (w == wv) kw &= lowmask;
            sup |= row[w] & kw;
        }
        bool nk = valid && (sup == 0ull);
        if (nk != keep) changed = 1;
        keep = nk;
        __syncthreads();
        if (!changed) break;
    }
    if (tid < TOPK) {
        float x1 = boxK[tid * 4 + 0], y1 = boxK[tid * 4 + 1];
        float x2 = boxK[tid * 4 + 2], y2 = boxK[tid * 4 + 3];
        float sc = scoreK[tid];
        out[tid * 5 + 0] = keep ? x1 : 0.0f;
        out[tid * 5 + 1] = keep ? y1 : 0.0f;
        out[tid * 5 + 2] = keep ? x2 : 0.0f;
        out[tid * 5 + 3] = keep ? y2 : 0.0f;
        out[tid * 5 + 4] = keep ? sc : 0.0f;
    }
}

extern "C" void kernel_launch(void* const* d_in, const int* in_sizes, int n_in,
                              void* d_out, int out_size, void* d_ws, size_t ws_size,
                              hipStream_t stream) {
    const float* logits = (const float*)d_in[0];
    const float* boxes  = (const float*)d_in[1];
    float* out = (float*)d_out;
    int nrows = in_sizes[0] / N_CLS;   // 200000

    char* w = (char*)d_ws;
    unsigned* cnt    = (unsigned*)(w + OFF_CNT);
    unsigned* cnt2   = (unsigned*)(w + OFF_CNT2);
    unsigned* tick1  = (unsigned*)(w + OFF_TICK1);
    unsigned* tick2  = (unsigned*)(w + OFF_TICK2);
    unsigned* tick3  = (unsigned*)(w + OFF_TICK3);
    unsigned* tick4  = (unsigned*)(w + OFF_TICK4);
    int*      psB    = (int*)(w + OFF_SB);
    unsigned* pCA    = (unsigned*)(w + OFF_CA);
    unsigned* ptb    = (unsigned*)(w + OFF_TB);
    unsigned* ghist  = (unsigned*)(w + OFF_GH);
    unsigned* rhist  = (unsigned*)(w + OFF_RH);
    u64* sel         = (u64*)(w + OFF_SEL);
    u64* sel2        = (u64*)(w + OFF_SEL2);
    float* boxK      = (float*)(w + OFF_BOX);
    float* scoreK    = (float*)(w + OFF_SCORE);
    int* clsK        = (int*)(w + OFF_CLS);
    u64* mask        = (u64*)(w + OFF_MASK);

    hipMemsetAsync(w, 0, MEMSET_BYTES, stream);

    int nblk = (nrows + ROWS_PER_BLK - 1) / ROWS_PER_BLK;   // 1563
    k_pass1<<<nblk, 256, 0, stream>>>(logits, nrows, sel, cnt, ghist, tick1, psB, pCA);
    k_refine<<<256, 256, 0, stream>>>(sel, cnt, rhist, tick2, psB, pCA, ptb);
    k_select_rank<<<128, 1024, 0, stream>>>(sel, cnt, ptb, sel2, cnt2, tick3,
                                            boxes, boxK, scoreK, clsK);
    k_conflict_nms<<<16, 1024, 0, stream>>>(boxK, clsK, scoreK, mask, tick4, out);
}

// Round 9
// 233.286 us; speedup vs baseline: 2.7694x; 1.0951x over previous
//
#include <hip/hip_runtime.h>
#include <stdint.h>
#include <math.h>

#define N_CLS    81
#define TOPK     1000
#define LISTCAP  (1u << 21)     // 2M candidate keys (16 MB)
#define CAP2     16384          // final selection capacity
#define RANKCAP  4096           // bitonic sort capacity (LDS, 32 KB)
#define SCORE_TH 0.05f
#define IMG_W    1333.0f
#define IMG_H    800.0f
#define GH_REP   8              // coarse-hist replicas (atomic spread)

// coarse bucket = float_bits >> 19, range for (0.05, 1.0] is [1961, 2032]
#define GH_BASE  1905           // ghist index = (bits>>19) - GH_BASE, in [56,127]

// workspace layout (byte offsets)
#define OFF_CNT    0                       // u32 total candidates
#define OFF_CNT2   8                       // u32 selected count
#define OFF_ARRV   16                      // u32 first-arrival ticket (K2 P0)
#define OFF_TICKA  20                      // u32 phase-A ticket
#define OFF_TICKB  24                      // u32 phase-B ticket
#define OFF_TICKC  28                      // u32 phase-C ticket
#define OFF_PBCA   32                      // u64 packed {flag63, CA[62:32], B+1[31:0]}
#define OFF_TB     40                      // u32 packed {flag31, tb[30:0]}
#define OFF_FLAGB  44                      // u32 boxes-ready flag
#define OFF_GH     64                      // u32[GH_REP][128] coarse hist (4096 B)
#define OFF_RH     4608                    // u32[1024] refined hist (4096 B)
#define MEMSET_BYTES 8704
#define OFF_SEL    16768                   // u64[LISTCAP]
#define OFF_SEL2   16793984                // u64[CAP2]
#define OFF_BOX    16925056                // u64[1000*2] packed clipped boxes
#define OFF_SCORE  16941056                // u32[1000] score bits
#define OFF_CLS    16945056                // i32[1000]
#define OFF_MASK   16949056                // u64[1000*16] conflict bit matrix

#define ROWS_PER_BLK 128
#define TILE_FLOATS  (ROWS_PER_BLK * N_CLS)   // 10368 floats = 41472 B (16B-aligned)
#define CBUF_CAP     1024
#define TAIL_BLOCKS  128                   // co-resident: 2 blocks/CU cap = 512 >= 128

typedef unsigned long long u64;

// direct global->LDS 16B DMA (m97 pattern): LDS dest = wave-uniform base + lane*16
__device__ __forceinline__ void gload_lds16(const float* g, float* l) {
    __builtin_amdgcn_global_load_lds(
        (const __attribute__((address_space(1))) unsigned int*)g,
        (__attribute__((address_space(3))) unsigned int*)l, 16, 0, 0);
}

// Device-scope atomics operate at the device coherence point (cross-XCD
// coherent, G12/m20; round-8 validated the store->ticket->load pattern).
// NO __threadfence() anywhere: a device fence forces a per-XCD L2
// writeback/invalidate on non-coherent-L2 gfx950 (rounds 3/4/5/7 poison).
__device__ __forceinline__ unsigned agent_load_u32(const unsigned* p) {
    return __hip_atomic_load(p, __ATOMIC_RELAXED, __HIP_MEMORY_SCOPE_AGENT);
}
__device__ __forceinline__ u64 agent_load_u64(const u64* p) {
    return __hip_atomic_load(p, __ATOMIC_RELAXED, __HIP_MEMORY_SCOPE_AGENT);
}
__device__ __forceinline__ void agent_store_u32(unsigned* p, unsigned v) {
    __hip_atomic_store(p, v, __ATOMIC_RELAXED, __HIP_MEMORY_SCOPE_AGENT);
}
__device__ __forceinline__ void agent_store_u64(u64* p, u64 v) {
    __hip_atomic_store(p, v, __ATOMIC_RELAXED, __HIP_MEMORY_SCOPE_AGENT);
}
__device__ __forceinline__ void drain_vm() {
    asm volatile("s_waitcnt vmcnt(0)" ::: "memory");
}

// ------- K1: round-2 pass1 VERBATIM (proven 52us; no ticket, no winner work) -------
__global__ __launch_bounds__(256) void k_pass1(
        const float* __restrict__ logits, int nrows,
        u64* __restrict__ sel, unsigned* __restrict__ cnt,
        unsigned* __restrict__ ghist) {
    __shared__ float tile[TILE_FLOATS];
    __shared__ unsigned lh[128];
    __shared__ u64 cbuf[CBUF_CAP];
    __shared__ unsigned lcnt, gbase;
    int tid = threadIdx.x, wv = tid >> 6, ln = tid & 63;
    for (int i = tid; i < 128; i += 256) lh[i] = 0;
    if (tid == 0) lcnt = 0;

    int base = blockIdx.x * ROWS_PER_BLK;
    int nr = nrows - base; if (nr > ROWS_PER_BLK) nr = ROWS_PER_BLK;
    const float* gtile = logits + (size_t)base * N_CLS;

    if (nr == ROWS_PER_BLK) {
        // 10 iterations x 4 waves x 1KB = 40960 B coalesced direct-to-LDS
        #pragma unroll
        for (int it = 0; it < 10; ++it) {
            int c = it * 1024 + wv * 256;          // float offset, wave-uniform
            gload_lds16(gtile + c + ln * 4, tile + c);
        }
        if (tid < TILE_FLOATS - 10240) tile[10240 + tid] = gtile[10240 + tid];
    } else {
        for (int i = tid; i < nr * N_CLS; i += 256) tile[i] = gtile[i];
    }
    __syncthreads();   // drains vmcnt (global_load_lds) + lgkmcnt

    int r = tid >> 1, h = tid & 1;
    if (r < nr) {
        const int rb = r * N_CLS + h;              // first owned class in LDS
        float v[41];
        #pragma unroll
        for (int m = 0; m < 40; ++m) v[m] = tile[rb + 2 * m];
        v[40] = (h == 0) ? tile[rb + 80] : 0.0f;   // class 80 only exists for h=0

        // ---- row max (exact, order-free) ----
        float mx = v[0];
        #pragma unroll
        for (int m = 1; m < 40; ++m) mx = fmaxf(mx, v[m]);
        mx = fmaxf(mx, (h == 0) ? v[40] : v[0]);
        float om = __shfl_xor(mx, 1);
        float mrow = fmaxf(mx, om);

        // ---- exps (op-identical to reference kernel) ----
        #pragma unroll
        for (int m = 0; m < 40; ++m) v[m] = expf(v[m] - mrow);
        v[40] = (h == 0) ? expf(v[40] - mrow) : 0.0f;

        // ---- per-thread bitrev subtree over leaves l = h + 2*b ----
        float stk0 = 0.f, stk1 = 0.f, stk2 = 0.f, stk3 = 0.f, stk4 = 0.f;
        float S = 0.f;
        #pragma unroll
        for (int i = 0; i < 32; ++i) {
            const int b = ((i & 1) << 4) | ((i & 2) << 2) | (i & 4) |
                          ((i & 8) >> 2) | ((i & 16) >> 4);   // bitrev5(i)
            float x = v[b];
            if (b < 8) x += v[b + 32];
            else if (b == 8) x = (h == 0) ? x + v[40] : x;
            if (i & 1) { x = stk0 + x;
              if (i & 2) { x = stk1 + x;
                if (i & 4) { x = stk2 + x;
                  if (i & 8) { x = stk3 + x;
                    if (i & 16) { S = stk4 + x; } else stk4 = x;
                  } else stk3 = x;
                } else stk2 = x;
              } else stk1 = x;
            } else stk0 = x;
        }
        float oS = __shfl_xor(S, 1);
        float s = (h == 0) ? (S + oS) : (oS + S);  // exact top-level association

        // ---- emit: conservative pre-filter, then bit-exact p>0.05 ----
        float eth = 0.0499f * s;                   // 0.2% margin >> fp rounding
        unsigned rowflat = (unsigned)(base + r) * N_CLS + (unsigned)h;
        #pragma unroll
        for (int m = 0; m < 41; ++m) {             // COMPILE-TIME v[] index only
            float e = v[m];
            if ((m + h) != 0 && e > eth) {         // skip background (h=0,m=0)
                float p = e / s;                   // identical division
                if (p > SCORE_TH) {
                    unsigned fb = __float_as_uint(p);
                    atomicAdd(&lh[(fb >> 19) - GH_BASE], 1u);
                    u64 key = ((u64)fb << 32) | (u64)(0xFFFFFFu - (rowflat + 2u * (unsigned)m));
                    unsigned pos = atomicAdd(&lcnt, 1u);
                    if (pos < CBUF_CAP) cbuf[pos] = key;
                    else { unsigned gp = atomicAdd(cnt, 1u); if (gp < LISTCAP) sel[gp] = key; }
                }
            }
        }
    }
    __syncthreads();
    unsigned* gh = ghist + (blockIdx.x & (GH_REP - 1)) * 128;
    for (int i = tid; i < 128; i += 256) {
        unsigned vv = lh[i];
        if (vv) atomicAdd(&gh[i], vv);
    }
    unsigned total = lcnt; if (total > CBUF_CAP) total = CBUF_CAP;
    if (tid == 0) gbase = atomicAdd(cnt, total);
    __syncthreads();
    unsigned gb = gbase;
    for (unsigned i = tid; i < total; i += 256) {
        unsigned gp = gb + i;
        if (gp < LISTCAP) sel[gp] = cbuf[i];
    }
}

// ------- K2: fused tail. 128 co-resident blocks x 1024 threads, 4 phases -------
// P0: first-arrival block -> coarse B/CA from ghist, publish packed u64.
// PA: all blocks histogram sel in bucket B -> rhist; winner-a -> exact tb (flag|tb).
// PB: all blocks compact sel>=tb -> sel2; winner-b bitonic-sorts, decodes boxes.
// PC: blocks 0..15 conflict masks; winner-c Jacobi NMS -> out.
// Spin-safety: 128 blocks, 16 waves, ~44KB LDS -> 2 blocks/CU cap (512) => all
// co-resident. All cross-block data via device-coherence-point atomics
// (round-8-validated primitives); flag bits packed with payload words.
__global__ __launch_bounds__(1024) void k_tail(
        char* __restrict__ ws, const float* __restrict__ boxes,
        float* __restrict__ out) {
    unsigned* cnt   = (unsigned*)(ws + OFF_CNT);
    unsigned* cnt2  = (unsigned*)(ws + OFF_CNT2);
    unsigned* arrv  = (unsigned*)(ws + OFF_ARRV);
    unsigned* tickA = (unsigned*)(ws + OFF_TICKA);
    unsigned* tickB = (unsigned*)(ws + OFF_TICKB);
    unsigned* tickC = (unsigned*)(ws + OFF_TICKC);
    u64*      pbca  = (u64*)(ws + OFF_PBCA);
    unsigned* ptb   = (unsigned*)(ws + OFF_TB);
    unsigned* flagB = (unsigned*)(ws + OFF_FLAGB);
    unsigned* ghist = (unsigned*)(ws + OFF_GH);
    unsigned* rhist = (unsigned*)(ws + OFF_RH);
    u64*      sel   = (u64*)(ws + OFF_SEL);
    u64*      sel2  = (u64*)(ws + OFF_SEL2);
    u64*      boxB  = (u64*)(ws + OFF_BOX);
    unsigned* scrB  = (unsigned*)(ws + OFF_SCORE);
    unsigned* clsB  = (unsigned*)(ws + OFF_CLS);
    u64*      mask  = (u64*)(ws + OFF_MASK);

    __shared__ unsigned lh[1024];
    __shared__ unsigned scu[1024], sfu[1024];
    __shared__ union {                      // ch (PB sort)  |  c (PC boxes)
        u64 ch[RANKCAP];                    // 32 KB
        struct { float4 box[TOPK]; int cls[TOPK]; unsigned sc[TOPK]; } c;  // 24 KB
    } shu;
    __shared__ u64 words[16];
    __shared__ int schanged, swB;
    __shared__ unsigned swCA, sarr, stk, sfl, stb;
    __shared__ u64 spb;

    int tid = threadIdx.x, ln = tid & 63;
    unsigned nb = gridDim.x;

    // ---------------- P0: first-arrival computes coarse B, CA ----------------
    if (tid == 0) sarr = atomicAdd(arrv, 1u);
    __syncthreads();
    if (sarr == 0) {
        if (tid < 128) {
            unsigned c = 0;
            #pragma unroll
            for (int rr = 0; rr < GH_REP; ++rr) c += ghist[rr * 128 + tid];  // cross-kernel
            scu[tid] = c; sfu[tid] = c;
        }
        if (tid == 0) swB = -1;
        __syncthreads();
        #pragma unroll
        for (int off = 1; off < 128; off <<= 1) {
            unsigned a = 0;
            if (tid < 128) a = (tid + off < 128) ? sfu[tid + off] : 0u;
            __syncthreads();
            if (tid < 128) sfu[tid] += a;
            __syncthreads();
        }
        if (tid == 0) swCA = sfu[0];                   // total (B<0 fallback)
        __syncthreads();
        if (tid < 128) {
            unsigned incl = sfu[tid], excl = incl - scu[tid];
            if (excl < TOPK && incl >= TOPK) { swB = tid; swCA = excl; }
        }
        __syncthreads();
        if (tid == 0) {
            u64 pk = (1ull << 63) | ((u64)(swCA & 0x7FFFFFFFu) << 32)
                                  | (u64)(unsigned)(swB + 1);
            agent_store_u64(pbca, pk);
        }
    }
    if (tid == 0) {
        u64 v;
        do { __builtin_amdgcn_s_sleep(1); v = agent_load_u64(pbca); } while (!(v >> 63));
        spb = v;
    }
    __syncthreads();
    int B = (int)(unsigned)(spb & 0xFFFFFFFFull) - 1;
    unsigned CA = (unsigned)((spb >> 32) & 0x7FFFFFFFull);
    unsigned M = *cnt; if (M > LISTCAP) M = LISTCAP;   // cross-kernel plain load
    unsigned stride = nb * 1024u;

    // ---------------- PA: refined 1024-bin hist inside bucket B ----------------
    if (B >= 0) {
        lh[tid] = 0;
        __syncthreads();
        unsigned Bbits = (unsigned)(B + GH_BASE);
        for (unsigned i = blockIdx.x * 1024u + tid; i < M; i += stride) {
            unsigned bv = (unsigned)(sel[i] >> 32);    // cross-kernel plain load
            if ((bv >> 19) == Bbits) atomicAdd(&lh[(bv >> 9) & 1023u], 1u);
        }
        __syncthreads();
        unsigned vv = lh[tid];
        if (vv) atomicAdd(&rhist[tid], vv);
    }
    __syncthreads();                                   // implies vmcnt(0) drain
    if (tid == 0) stk = atomicAdd(tickA, 1u);
    __syncthreads();
    if (stk == nb - 1) {                               // winner-a: exact tb
        unsigned c = (B >= 0) ? agent_load_u32(&rhist[tid]) : 0u;
        scu[tid] = c; sfu[tid] = c;
        if (tid == 0) stb = 0;
        __syncthreads();
        #pragma unroll
        for (int off = 1; off < 1024; off <<= 1) {
            unsigned a = (tid + off < 1024) ? sfu[tid + off] : 0u;
            __syncthreads();
            sfu[tid] += a;
            __syncthreads();
        }
        unsigned incl = sfu[tid], excl = incl - scu[tid];
        if (B >= 0 && CA + excl < TOPK && CA + incl >= TOPK)
            stb = ((unsigned)(B + GH_BASE) << 19) | ((unsigned)tid << 9);
        __syncthreads();
        if (tid == 0) agent_store_u32(ptb, stb | 0x80000000u);
    }

    // ---------------- PB: compact sel >= tb -> sel2; winner-b sorts ----------------
    if (tid == 0) {
        unsigned f;
        do { __builtin_amdgcn_s_sleep(1); f = agent_load_u32(ptb); } while (!(f & 0x80000000u));
        sfl = f;
    }
    __syncthreads();
    unsigned tb = sfl & 0x7FFFFFFFu;
    for (unsigned ibase = blockIdx.x * 1024u; ibase < M; ibase += stride) {
        unsigned i = ibase + tid;
        bool act = (i < M);
        u64 key = act ? sel[i] : 0ull;
        bool c = act && ((unsigned)(key >> 32) >= tb);
        u64 b = __ballot(c);
        int n = __popcll(b);
        if (n) {
            unsigned wb = 0;
            if (ln == 0) wb = atomicAdd(cnt2, (unsigned)n);
            wb = __shfl(wb, 0);
            if (c) {
                unsigned pos = wb + (unsigned)__popcll(b & ((1ull << ln) - 1ull));
                if (pos < CAP2) agent_store_u64(&sel2[pos], key);
            }
        }
    }
    __syncthreads();
    if (tid == 0) stk = atomicAdd(tickB, 1u);
    __syncthreads();
    if (stk == nb - 1) {                               // winner-b: sort + decode
        unsigned S = agent_load_u32(cnt2); if (S > CAP2) S = CAP2;
        if (S <= RANKCAP) {
            for (unsigned i = tid; i < RANKCAP; i += 1024)
                shu.ch[i] = (i < S) ? agent_load_u64(&sel2[i]) : 0ull;
            __syncthreads();
            for (unsigned k = 2; k <= RANKCAP; k <<= 1) {      // descending
                for (unsigned j = k >> 1; j > 0; j >>= 1) {
                    #pragma unroll
                    for (unsigned ii = 0; ii < RANKCAP / 1024; ++ii) {
                        unsigned i = ii * 1024 + tid;
                        unsigned ixj = i ^ j;
                        if (ixj > i) {
                            u64 a = shu.ch[i], b = shu.ch[ixj];
                            bool sw = ((i & k) == 0) ? (a < b) : (a > b);
                            if (sw) { shu.ch[i] = b; shu.ch[ixj] = a; }
                        }
                    }
                    __syncthreads();
                }
            }
            if (tid < TOPK) {
                u64 key = shu.ch[tid];
                float x1 = 0.f, y1 = 0.f, x2 = 0.f, y2 = 0.f, sc = 0.f;
                int cls = -1;
                if (key != 0ull) {
                    sc = __uint_as_float((unsigned)(key >> 32));
                    unsigned fi = 0xFFFFFFu - (unsigned)(key & 0xFFFFFFFFull);
                    unsigned prop = fi / N_CLS;
                    cls = (int)(fi - prop * N_CLS);
                    const float* bx = boxes + (size_t)prop * 4;
                    x1 = fminf(fmaxf(bx[0], 0.0f), IMG_W - 1.0f);
                    y1 = fminf(fmaxf(bx[1], 0.0f), IMG_H - 1.0f);
                    x2 = fminf(fmaxf(bx[2], 0.0f), IMG_W - 1.0f);
                    y2 = fminf(fmaxf(bx[3], 0.0f), IMG_H - 1.0f);
                }
                agent_store_u64(&boxB[tid * 2],
                    ((u64)__float_as_uint(y1) << 32) | __float_as_uint(x1));
                agent_store_u64(&boxB[tid * 2 + 1],
                    ((u64)__float_as_uint(y2) << 32) | __float_as_uint(x2));
                agent_store_u32(&scrB[tid], __float_as_uint(sc));
                agent_store_u32(&clsB[tid], (unsigned)cls);
            }
        } else {
            // fallback: counting rank (practically unreachable; 512-ULP bin)
            for (unsigned t2i = tid; t2i < TOPK; t2i += 1024) {  // defaults first
                agent_store_u64(&boxB[t2i * 2], 0ull);
                agent_store_u64(&boxB[t2i * 2 + 1], 0ull);
                agent_store_u32(&scrB[t2i], 0u);
                agent_store_u32(&clsB[t2i], (unsigned)-1);
            }
            for (unsigned s0 = 0; s0 < S; s0 += 1024) {
                unsigned t2 = s0 + tid;
                u64 my = (t2 < S) ? agent_load_u64(&sel2[t2]) : 0ull;
                int r = 0;
                for (unsigned c0 = 0; c0 < S; c0 += RANKCAP) {
                    unsigned n = S - c0; if (n > RANKCAP) n = RANKCAP;
                    __syncthreads();
                    for (unsigned i = tid; i < n; i += 1024)
                        shu.ch[i] = agent_load_u64(&sel2[c0 + i]);
                    __syncthreads();
                    if (t2 < S)
                        for (unsigned jj = 0; jj < n; jj++) r += (shu.ch[jj] > my) ? 1 : 0;
                }
                if (t2 < S && r < TOPK) {
                    float sc = __uint_as_float((unsigned)(my >> 32));
                    unsigned fi = 0xFFFFFFu - (unsigned)(my & 0xFFFFFFFFull);
                    unsigned prop = fi / N_CLS;
                    int cls = (int)(fi - prop * N_CLS);
                    const float* bx = boxes + (size_t)prop * 4;
                    float x1 = fminf(fmaxf(bx[0], 0.0f), IMG_W - 1.0f);
                    float y1 = fminf(fmaxf(bx[1], 0.0f), IMG_H - 1.0f);
                    float x2 = fminf(fmaxf(bx[2], 0.0f), IMG_W - 1.0f);
                    float y2 = fminf(fmaxf(bx[3], 0.0f), IMG_H - 1.0f);
                    agent_store_u64(&boxB[r * 2],
                        ((u64)__float_as_uint(y1) << 32) | __float_as_uint(x1));
                    agent_store_u64(&boxB[r * 2 + 1],
                        ((u64)__float_as_uint(y2) << 32) | __float_as_uint(x2));
                    agent_store_u32(&scrB[r], __float_as_uint(sc));
                    agent_store_u32(&clsB[r], (unsigned)cls);
                }
            }
        }
        __syncthreads();
        drain_vm();                                    // boxB/scr/cls acked
        if (tid == 0) agent_store_u32(flagB, 1u);
    }

    // ---------------- PC: conflict masks (blocks 0..15) + Jacobi NMS ----------------
    if (blockIdx.x >= 16) return;
    if (tid == 0) {
        unsigned f;
        do { __builtin_amdgcn_s_sleep(1); f = agent_load_u32(flagB); } while (!f);
        sfl = f;
    }
    __syncthreads();
    if (tid < TOPK) {
        u64 a = agent_load_u64(&boxB[tid * 2]);
        u64 b = agent_load_u64(&boxB[tid * 2 + 1]);
        shu.c.box[tid] = make_float4(
            __uint_as_float((unsigned)a), __uint_as_float((unsigned)(a >> 32)),
            __uint_as_float((unsigned)b), __uint_as_float((unsigned)(b >> 32)));
        shu.c.cls[tid] = (int)agent_load_u32(&clsB[tid]);
        shu.c.sc[tid]  = agent_load_u32(&scrB[tid]);
    }
    __syncthreads();
    {
        int t = blockIdx.x * 1024 + tid;
        int i = t >> 4, w = t & 15;
        if (i < TOPK) {
            float4 bi = shu.c.box[i];
            int ci = shu.c.cls[i];
            float ai = (bi.z - bi.x) * (bi.w - bi.y);
            u64 m = 0;
            int jbase = w << 6;
            for (int jj = 0; jj < 64; jj++) {
                int j = jbase + jj;
                if (j >= TOPK) break;
                float4 bj = shu.c.box[j];
                float aj = (bj.z - bj.x) * (bj.w - bj.y);
                float ww = fmaxf(fminf(bi.z, bj.z) - fmaxf(bi.x, bj.x), 0.0f);
                float hh = fmaxf(fminf(bi.w, bj.w) - fmaxf(bi.y, bj.y), 0.0f);
                float inter = ww * hh;
                float iou = inter / (ai + aj - inter + 1e-9f);
                if (iou > 0.5f && ci == shu.c.cls[j]) m |= (1ull << jj);
            }
            agent_store_u64(&mask[(size_t)i * 16 + w], m);
        }
    }
    __syncthreads();                                   // implies vmcnt drain
    if (tid == 0) stk = atomicAdd(tickC, 1u);
    __syncthreads();
    if (stk != 15u) return;

    // ---- winner-c (1024 threads): Jacobi fixed-point of greedy NMS ----
    int wv = tid >> 6;
    bool valid = (tid < TOPK) && (__uint_as_float(shu.c.sc[tid]) > 0.0f);
    u64 row[16];
    #pragma unroll
    for (int w = 0; w < 16; w++)
        row[w] = (tid < TOPK) ? agent_load_u64(&mask[(size_t)tid * 16 + w]) : 0ull;
    u64 lowmask = (1ull << ln) - 1ull;
    bool keep = valid;
    for (int it = 0; it < 1024; ++it) {
        u64 b = __ballot(keep);
        if (ln == 0) words[wv] = b;
        if (tid == 0) schanged = 0;
        __syncthreads();
        u64 sup = 0;
        for (int w = 0; w <= wv; w++) {                // wv is wave-uniform
            u64 kw = words[w];
            if (w == wv) kw &= lowmask;
            sup |= row[w] & kw;
        }
        bool nk = valid && (sup == 0ull);
        if (nk != keep) schanged = 1;
        keep = nk;
        __syncthreads();
        if (!schanged) break;
    }
    if (tid < TOPK) {
        float4 bx = shu.c.box[tid];
        float sc = __uint_as_float(shu.c.sc[tid]);
        out[tid * 5 + 0] = keep ? bx.x : 0.0f;
        out[tid * 5 + 1] = keep ? bx.y : 0.0f;
        out[tid * 5 + 2] = keep ? bx.z : 0.0f;
        out[tid * 5 + 3] = keep ? bx.w : 0.0f;
        out[tid * 5 + 4] = keep ? sc : 0.0f;
    }
}

extern "C" void kernel_launch(void* const* d_in, const int* in_sizes, int n_in,
                              void* d_out, int out_size, void* d_ws, size_t ws_size,
                              hipStream_t stream) {
    const float* logits = (const float*)d_in[0];
    const float* boxes  = (const float*)d_in[1];
    float* out = (float*)d_out;
    int nrows = in_sizes[0] / N_CLS;   // 200000

    char* w = (char*)d_ws;
    unsigned* cnt   = (unsigned*)(w + OFF_CNT);
    unsigned* ghist = (unsigned*)(w + OFF_GH);
    u64* sel        = (u64*)(w + OFF_SEL);

    hipMemsetAsync(w, 0, MEMSET_BYTES, stream);

    int nblk = (nrows + ROWS_PER_BLK - 1) / ROWS_PER_BLK;   // 1563
    k_pass1<<<nblk, 256, 0, stream>>>(logits, nrows, sel, cnt, ghist);
    k_tail<<<TAIL_BLOCKS, 1024, 0, stream>>>(w, boxes, out);
}

// Round 10
// 196.443 us; speedup vs baseline: 3.2888x; 1.1876x over previous
//
#include <hip/hip_runtime.h>
#include <stdint.h>
#include <math.h>

#define N_CLS    81
#define TOPK     1000
#define LISTCAP  (1u << 21)     // 2M candidate keys (16 MB)
#define CAP2     16384          // final selection capacity
#define SCORE_TH 0.05f
#define IMG_W    1333.0f
#define IMG_H    800.0f
#define GH_REP   8              // coarse-hist replicas (atomic spread)

// coarse bucket = float_bits >> 19, range for (0.05, 1.0] is [1961, 2032]
#define GH_BASE  1905           // ghist index = (bits>>19) - GH_BASE, in [56,127]

// workspace layout (byte offsets). Control scalars on separate 128B lines so
// 128 spinners don't contend with compact counters at the coherence point.
#define OFF_CNT    0                       // u32 total candidates
#define OFF_CNT2   128                     // u32 selected count
#define OFF_ARRV   256                     // u32 first-arrival ticket
#define OFF_TICKA  384                     // u32 refine-path ticket
#define OFF_TICKB  512                     // u32 post-compact ticket
#define OFF_TICKR  640                     // u32 post-rank ticket
#define OFF_TICKC  768                     // u32 mask ticket
#define OFF_PBCA   896                     // u64 packed {flag63, inB[39:18], CA[17:8], B+1[7:0]}
#define OFF_TB     1024                    // u32 packed {flag31, tb[30:0]} (refine path)
#define OFF_GH     1280                    // u32[GH_REP][128] coarse hist (4096 B)
#define OFF_RH     5376                    // u32[1024] refined hist (4096 B)
#define MEMSET_BYTES 9472
#define OFF_SEL    16768                   // u64[LISTCAP]
#define OFF_SEL2   16793984                // u64[CAP2]
#define OFF_BOX    16925056                // u64[1000*2] packed clipped boxes
#define OFF_SCORE  16941056                // u32[1000] score bits
#define OFF_CLS    16945056                // i32[1000]
#define OFF_MASK   16949056                // u64[1000*16] conflict bit matrix

#define ROWS_PER_BLK 128
#define TILE_FLOATS  (ROWS_PER_BLK * N_CLS)   // 10368 floats = 41472 B (16B-aligned)
#define CBUF_CAP     1024
#define TAIL_BLOCKS  128                   // co-resident: 2 blocks/CU cap = 512 >= 128

typedef unsigned long long u64;

// direct global->LDS 16B DMA (m97 pattern): LDS dest = wave-uniform base + lane*16
__device__ __forceinline__ void gload_lds16(const float* g, float* l) {
    __builtin_amdgcn_global_load_lds(
        (const __attribute__((address_space(1))) unsigned int*)g,
        (__attribute__((address_space(3))) unsigned int*)l, 16, 0, 0);
}

// Device-scope atomics operate at the device coherence point (cross-XCD
// coherent, G12/m20; round-8/9 validated the drain->ticket->load pattern).
// NO __threadfence() anywhere: a device fence forces a per-XCD L2
// writeback/invalidate on non-coherent-L2 gfx950 (rounds 3/4/5/7 poison).
__device__ __forceinline__ unsigned agent_load_u32(const unsigned* p) {
    return __hip_atomic_load(p, __ATOMIC_RELAXED, __HIP_MEMORY_SCOPE_AGENT);
}
__device__ __forceinline__ u64 agent_load_u64(const u64* p) {
    return __hip_atomic_load(p, __ATOMIC_RELAXED, __HIP_MEMORY_SCOPE_AGENT);
}
__device__ __forceinline__ void agent_store_u32(unsigned* p, unsigned v) {
    __hip_atomic_store(p, v, __ATOMIC_RELAXED, __HIP_MEMORY_SCOPE_AGENT);
}
__device__ __forceinline__ void agent_store_u64(u64* p, u64 v) {
    __hip_atomic_store(p, v, __ATOMIC_RELAXED, __HIP_MEMORY_SCOPE_AGENT);
}
__device__ __forceinline__ void drain_vm() {
    asm volatile("s_waitcnt vmcnt(0)" ::: "memory");
}

// ------- K1: round-2 pass1 VERBATIM (proven fast; no ticket, no winner work) -------
__global__ __launch_bounds__(256) void k_pass1(
        const float* __restrict__ logits, int nrows,
        u64* __restrict__ sel, unsigned* __restrict__ cnt,
        unsigned* __restrict__ ghist) {
    __shared__ float tile[TILE_FLOATS];
    __shared__ unsigned lh[128];
    __shared__ u64 cbuf[CBUF_CAP];
    __shared__ unsigned lcnt, gbase;
    int tid = threadIdx.x, wv = tid >> 6, ln = tid & 63;
    for (int i = tid; i < 128; i += 256) lh[i] = 0;
    if (tid == 0) lcnt = 0;

    int base = blockIdx.x * ROWS_PER_BLK;
    int nr = nrows - base; if (nr > ROWS_PER_BLK) nr = ROWS_PER_BLK;
    const float* gtile = logits + (size_t)base * N_CLS;

    if (nr == ROWS_PER_BLK) {
        // 10 iterations x 4 waves x 1KB = 40960 B coalesced direct-to-LDS
        #pragma unroll
        for (int it = 0; it < 10; ++it) {
            int c = it * 1024 + wv * 256;          // float offset, wave-uniform
            gload_lds16(gtile + c + ln * 4, tile + c);
        }
        if (tid < TILE_FLOATS - 10240) tile[10240 + tid] = gtile[10240 + tid];
    } else {
        for (int i = tid; i < nr * N_CLS; i += 256) tile[i] = gtile[i];
    }
    __syncthreads();   // drains vmcnt (global_load_lds) + lgkmcnt

    int r = tid >> 1, h = tid & 1;
    if (r < nr) {
        const int rb = r * N_CLS + h;              // first owned class in LDS
        float v[41];
        #pragma unroll
        for (int m = 0; m < 40; ++m) v[m] = tile[rb + 2 * m];
        v[40] = (h == 0) ? tile[rb + 80] : 0.0f;   // class 80 only exists for h=0

        // ---- row max (exact, order-free) ----
        float mx = v[0];
        #pragma unroll
        for (int m = 1; m < 40; ++m) mx = fmaxf(mx, v[m]);
        mx = fmaxf(mx, (h == 0) ? v[40] : v[0]);
        float om = __shfl_xor(mx, 1);
        float mrow = fmaxf(mx, om);

        // ---- exps (op-identical to reference kernel) ----
        #pragma unroll
        for (int m = 0; m < 40; ++m) v[m] = expf(v[m] - mrow);
        v[40] = (h == 0) ? expf(v[40] - mrow) : 0.0f;

        // ---- per-thread bitrev subtree over leaves l = h + 2*b ----
        float stk0 = 0.f, stk1 = 0.f, stk2 = 0.f, stk3 = 0.f, stk4 = 0.f;
        float S = 0.f;
        #pragma unroll
        for (int i = 0; i < 32; ++i) {
            const int b = ((i & 1) << 4) | ((i & 2) << 2) | (i & 4) |
                          ((i & 8) >> 2) | ((i & 16) >> 4);   // bitrev5(i)
            float x = v[b];
            if (b < 8) x += v[b + 32];
            else if (b == 8) x = (h == 0) ? x + v[40] : x;
            if (i & 1) { x = stk0 + x;
              if (i & 2) { x = stk1 + x;
                if (i & 4) { x = stk2 + x;
                  if (i & 8) { x = stk3 + x;
                    if (i & 16) { S = stk4 + x; } else stk4 = x;
                  } else stk3 = x;
                } else stk2 = x;
              } else stk1 = x;
            } else stk0 = x;
        }
        float oS = __shfl_xor(S, 1);
        float s = (h == 0) ? (S + oS) : (oS + S);  // exact top-level association

        // ---- emit: conservative pre-filter, then bit-exact p>0.05 ----
        float eth = 0.0499f * s;                   // 0.2% margin >> fp rounding
        unsigned rowflat = (unsigned)(base + r) * N_CLS + (unsigned)h;
        #pragma unroll
        for (int m = 0; m < 41; ++m) {             // COMPILE-TIME v[] index only
            float e = v[m];
            if ((m + h) != 0 && e > eth) {         // skip background (h=0,m=0)
                float p = e / s;                   // identical division
                if (p > SCORE_TH) {
                    unsigned fb = __float_as_uint(p);
                    atomicAdd(&lh[(fb >> 19) - GH_BASE], 1u);
                    u64 key = ((u64)fb << 32) | (u64)(0xFFFFFFu - (rowflat + 2u * (unsigned)m));
                    unsigned pos = atomicAdd(&lcnt, 1u);
                    if (pos < CBUF_CAP) cbuf[pos] = key;
                    else { unsigned gp = atomicAdd(cnt, 1u); if (gp < LISTCAP) sel[gp] = key; }
                }
            }
        }
    }
    __syncthreads();
    unsigned* gh = ghist + (blockIdx.x & (GH_REP - 1)) * 128;
    for (int i = tid; i < 128; i += 256) {
        unsigned vv = lh[i];
        if (vv) atomicAdd(&gh[i], vv);
    }
    unsigned total = lcnt; if (total > CBUF_CAP) total = CBUF_CAP;
    if (tid == 0) gbase = atomicAdd(cnt, total);
    __syncthreads();
    unsigned gb = gbase;
    for (unsigned i = tid; i < total; i += 256) {
        unsigned gp = gb + i;
        if (gp < LISTCAP) sel[gp] = cbuf[i];
    }
}

// ------- K2: fused tail, NO single-block monopoly phases -------
// P0: first-arrival block -> B, CA, inB from ghist; publish packed u64.
//     If CA+inB <= CAP2 (common): tb = coarse bucket floor, NO refine pass.
//     (Same top-1000: compacting a superset down to the crossing bucket floor
//      then exact-ranking is selection-equivalent to the refined threshold.)
// [fallback] refine hist + winner-computed tb only if the bucket is huge.
// PB: all 128 blocks compact sel>=tb -> sel2; global sync.
// PR: DISTRIBUTED rank+decode: wave-slot (128x16=2048) per key; 64 lanes count
//     {sel2[j] > my} coalesced, shfl-reduce, lane0 decodes into rank slot.
//     Replaces round-9's single-block 4096-bitonic sort (its 78 barrier stages
//     on one CU were the 116us kernel's long pole). Global sync.
// PC: blocks 0..15 conflict masks; last runs Jacobi NMS -> out.
__global__ __launch_bounds__(1024) void k_tail(
        char* __restrict__ ws, const float* __restrict__ boxes,
        float* __restrict__ out) {
    unsigned* cnt   = (unsigned*)(ws + OFF_CNT);
    unsigned* cnt2  = (unsigned*)(ws + OFF_CNT2);
    unsigned* arrv  = (unsigned*)(ws + OFF_ARRV);
    unsigned* tickA = (unsigned*)(ws + OFF_TICKA);
    unsigned* tickB = (unsigned*)(ws + OFF_TICKB);
    unsigned* tickR = (unsigned*)(ws + OFF_TICKR);
    unsigned* tickC = (unsigned*)(ws + OFF_TICKC);
    u64*      pbca  = (u64*)(ws + OFF_PBCA);
    unsigned* ptb   = (unsigned*)(ws + OFF_TB);
    unsigned* ghist = (unsigned*)(ws + OFF_GH);
    unsigned* rhist = (unsigned*)(ws + OFF_RH);
    u64*      sel   = (u64*)(ws + OFF_SEL);
    u64*      sel2  = (u64*)(ws + OFF_SEL2);
    u64*      boxB  = (u64*)(ws + OFF_BOX);
    unsigned* scrB  = (unsigned*)(ws + OFF_SCORE);
    unsigned* clsB  = (unsigned*)(ws + OFF_CLS);
    u64*      mask  = (u64*)(ws + OFF_MASK);

    __shared__ unsigned scu[1024], sfu[1024];
    __shared__ union {
        unsigned lhist[1024];               // refine fallback
        struct { float4 box[TOPK]; int cls[TOPK]; unsigned sc[TOPK]; } c;  // 24 KB
    } shu;
    __shared__ u64 words[16];
    __shared__ int schanged, swB;
    __shared__ unsigned swCA, swIB, sarr, stk, sfl, stb;
    __shared__ u64 spb;

    int tid = threadIdx.x, ln = tid & 63;
    unsigned nb = gridDim.x;

    // ---------------- P0: first-arrival computes B, CA, inB ----------------
    if (tid == 0) sarr = atomicAdd(arrv, 1u);
    __syncthreads();
    if (sarr == 0) {
        if (tid < 128) {
            unsigned c = 0;
            #pragma unroll
            for (int rr = 0; rr < GH_REP; ++rr) c += ghist[rr * 128 + tid];  // cross-kernel
            scu[tid] = c; sfu[tid] = c;
        }
        if (tid == 0) swB = -1;
        __syncthreads();
        #pragma unroll
        for (int off = 1; off < 128; off <<= 1) {
            unsigned a = 0;
            if (tid < 128) a = (tid + off < 128) ? sfu[tid + off] : 0u;
            __syncthreads();
            if (tid < 128) sfu[tid] += a;
            __syncthreads();
        }
        if (tid == 0) { swCA = sfu[0]; swIB = 0; }     // total (B<0 fallback)
        __syncthreads();
        if (tid < 128) {
            unsigned incl = sfu[tid], excl = incl - scu[tid];
            if (excl < TOPK && incl >= TOPK) { swB = tid; swCA = excl; swIB = scu[tid]; }
        }
        __syncthreads();
        if (tid == 0) {
            // pack: flag63 | inB[39:18] | CA[17:8] | (B+1)[7:0]; CA<=999, inB<=2^21
            u64 pk = (1ull << 63) | ((u64)swIB << 18)
                   | ((u64)(swCA & 0x3FFu) << 8) | (u64)(unsigned)(swB + 1);
            agent_store_u64(pbca, pk);
        }
    }
    if (tid == 0) {
        u64 v;
        do { __builtin_amdgcn_s_sleep(2); v = agent_load_u64(pbca); } while (!(v >> 63));
        spb = v;
    }
    __syncthreads();
    int B = (int)(unsigned)(spb & 0xFFull) - 1;
    unsigned CA  = (unsigned)((spb >> 8) & 0x3FFu);
    unsigned inB = (unsigned)((spb >> 18) & 0x3FFFFFu);
    unsigned M = *cnt; if (M > LISTCAP) M = LISTCAP;   // cross-kernel plain load
    unsigned stride = nb * 1024u;
    unsigned tb;

    if (B < 0 || CA + inB <= CAP2) {
        // ---------------- fast path: coarse bucket floor, no refine ----------------
        tb = (B < 0) ? 0u : ((unsigned)(B + GH_BASE) << 19);
    } else {
        // ---------------- fallback: refined 1024-bin hist -> exact tb ----------------
        shu.lhist[tid] = 0;
        __syncthreads();
        unsigned Bbits = (unsigned)(B + GH_BASE);
        for (unsigned i = blockIdx.x * 1024u + tid; i < M; i += stride) {
            unsigned bv = (unsigned)(sel[i] >> 32);
            if ((bv >> 19) == Bbits) atomicAdd(&shu.lhist[(bv >> 9) & 1023u], 1u);
        }
        __syncthreads();
        { unsigned vv = shu.lhist[tid]; if (vv) atomicAdd(&rhist[tid], vv); }
        __syncthreads();
        drain_vm();
        if (tid == 0) stk = atomicAdd(tickA, 1u);
        __syncthreads();
        if (stk == nb - 1) {                           // winner-a: exact tb
            unsigned c = agent_load_u32(&rhist[tid]);
            scu[tid] = c; sfu[tid] = c;
            if (tid == 0) stb = 0;
            __syncthreads();
            #pragma unroll
            for (int off = 1; off < 1024; off <<= 1) {
                unsigned a = (tid + off < 1024) ? sfu[tid + off] : 0u;
                __syncthreads();
                sfu[tid] += a;
                __syncthreads();
            }
            unsigned incl = sfu[tid], excl = incl - scu[tid];
            if (CA + excl < TOPK && CA + incl >= TOPK)
                stb = ((unsigned)(B + GH_BASE) << 19) | ((unsigned)tid << 9);
            __syncthreads();
            if (tid == 0) agent_store_u32(ptb, stb | 0x80000000u);
        }
        if (tid == 0) {
            unsigned f;
            do { __builtin_amdgcn_s_sleep(2); f = agent_load_u32(ptb); } while (!(f >> 31));
            sfl = f;
        }
        __syncthreads();
        tb = sfl & 0x7FFFFFFFu;
    }

    // ---------------- PB: compact sel >= tb -> sel2 ----------------
    for (unsigned ibase = blockIdx.x * 1024u; ibase < M; ibase += stride) {
        unsigned i = ibase + tid;
        bool act = (i < M);
        u64 key = act ? sel[i] : 0ull;
        bool c = act && ((unsigned)(key >> 32) >= tb);
        u64 b = __ballot(c);
        int n = __popcll(b);
        if (n) {
            unsigned wb = 0;
            if (ln == 0) wb = atomicAdd(cnt2, (unsigned)n);
            wb = __shfl(wb, 0);
            if (c) {
                unsigned pos = wb + (unsigned)__popcll(b & ((1ull << ln) - 1ull));
                if (pos < CAP2) agent_store_u64(&sel2[pos], key);
            }
        }
    }
    __syncthreads();
    drain_vm();
    if (tid == 0) {
        atomicAdd(tickB, 1u);
        unsigned v;
        do { __builtin_amdgcn_s_sleep(2); v = agent_load_u32(tickB); } while (v < nb);
    }
    __syncthreads();

    // ---------------- PR: distributed wave-per-key rank + decode ----------------
    {
        unsigned S = agent_load_u32(cnt2); if (S > CAP2) S = CAP2;
        unsigned slot = blockIdx.x * 16u + (unsigned)(tid >> 6);
        unsigned nslots = nb * 16u;                    // 2048 wave-slots
        unsigned lim = (S > TOPK) ? S : TOPK;
        for (unsigned k = slot; k < lim; k += nslots) {
            if (k < S) {
                u64 my = agent_load_u64(&sel2[k]);
                unsigned rk = 0;
                for (unsigned j = ln; j < S; j += 64)  // coalesced 512B/wave
                    rk += (agent_load_u64(&sel2[j]) > my) ? 1u : 0u;
                #pragma unroll
                for (int off = 32; off > 0; off >>= 1) rk += __shfl_xor(rk, off);
                if (ln == 0 && rk < TOPK) {
                    float sc = __uint_as_float((unsigned)(my >> 32));
                    unsigned fi = 0xFFFFFFu - (unsigned)(my & 0xFFFFFFFFull);
                    unsigned prop = fi / N_CLS;
                    int cls = (int)(fi - prop * N_CLS);
                    const float* bx = boxes + (size_t)prop * 4;
                    float x1 = fminf(fmaxf(bx[0], 0.0f), IMG_W - 1.0f);
                    float y1 = fminf(fmaxf(bx[1], 0.0f), IMG_H - 1.0f);
                    float x2 = fminf(fmaxf(bx[2], 0.0f), IMG_W - 1.0f);
                    float y2 = fminf(fmaxf(bx[3], 0.0f), IMG_H - 1.0f);
                    agent_store_u64(&boxB[rk * 2],
                        ((u64)__float_as_uint(y1) << 32) | __float_as_uint(x1));
                    agent_store_u64(&boxB[rk * 2 + 1],
                        ((u64)__float_as_uint(y2) << 32) | __float_as_uint(x2));
                    agent_store_u32(&scrB[rk], __float_as_uint(sc));
                    agent_store_u32(&clsB[rk], (unsigned)cls);
                }
            } else if (ln == 0) {                      // k in [S, TOPK): defaults
                agent_store_u64(&boxB[k * 2], 0ull);
                agent_store_u64(&boxB[k * 2 + 1], 0ull);
                agent_store_u32(&scrB[k], 0u);
                agent_store_u32(&clsB[k], (unsigned)-1);
            }
        }
    }
    __syncthreads();
    drain_vm();
    if (tid == 0) {
        atomicAdd(tickR, 1u);
        unsigned v;
        do { __builtin_amdgcn_s_sleep(2); v = agent_load_u32(tickR); } while (v < nb);
    }
    __syncthreads();

    // ---------------- PC: conflict masks (blocks 0..15) + Jacobi NMS ----------------
    if (blockIdx.x >= 16) return;
    if (tid < TOPK) {
        u64 a = agent_load_u64(&boxB[tid * 2]);
        u64 b = agent_load_u64(&boxB[tid * 2 + 1]);
        shu.c.box[tid] = make_float4(
            __uint_as_float((unsigned)a), __uint_as_float((unsigned)(a >> 32)),
            __uint_as_float((unsigned)b), __uint_as_float((unsigned)(b >> 32)));
        shu.c.cls[tid] = (int)agent_load_u32(&clsB[tid]);
        shu.c.sc[tid]  = agent_load_u32(&scrB[tid]);
    }
    __syncthreads();
    {
        int t = blockIdx.x * 1024 + tid;
        int i = t >> 4, w = t & 15;
        if (i < TOPK) {
            float4 bi = shu.c.box[i];
            int ci = shu.c.cls[i];
            float ai = (bi.z - bi.x) * (bi.w - bi.y);
            u64 m = 0;
            int jbase = w << 6;
            for (int jj = 0; jj < 64; jj++) {
                int j = jbase + jj;
                if (j >= TOPK) break;
                float4 bj = shu.c.box[j];
                float aj = (bj.z - bj.x) * (bj.w - bj.y);
                float ww = fmaxf(fminf(bi.z, bj.z) - fmaxf(bi.x, bj.x), 0.0f);
                float hh = fmaxf(fminf(bi.w, bj.w) - fmaxf(bi.y, bj.y), 0.0f);
                float inter = ww * hh;
                float iou = inter / (ai + aj - inter + 1e-9f);
                if (iou > 0.5f && ci == shu.c.cls[j]) m |= (1ull << jj);
            }
            agent_store_u64(&mask[(size_t)i * 16 + w], m);
        }
    }
    __syncthreads();
    drain_vm();
    if (tid == 0) stk = atomicAdd(tickC, 1u);
    __syncthreads();
    if (stk != 15u) return;

    // ---- winner (1024 threads): Jacobi fixed-point of greedy NMS ----
    int wv = tid >> 6;
    bool valid = (tid < TOPK) && (__uint_as_float(shu.c.sc[tid]) > 0.0f);
    u64 row[16];
    #pragma unroll
    for (int w = 0; w < 16; w++)
        row[w] = (tid < TOPK) ? agent_load_u64(&mask[(size_t)tid * 16 + w]) : 0ull;
    u64 lowmask = (1ull << ln) - 1ull;
    bool keep = valid;
    for (int it = 0; it < 1024; ++it) {
        u64 b = __ballot(keep);
        if (ln == 0) words[wv] = b;
        if (tid == 0) schanged = 0;
        __syncthreads();
        u64 sup = 0;
        for (int w = 0; w <= wv; w++) {                // wv is wave-uniform
            u64 kw = words[w];
            if (w == wv) kw &= lowmask;
            sup |= row[w] & kw;
        }
        bool nk = valid && (sup == 0ull);
        if (nk != keep) schanged = 1;
        keep = nk;
        __syncthreads();
        if (!schanged) break;
    }
    if (tid < TOPK) {
        float4 bx = shu.c.box[tid];
        float sc = __uint_as_float(shu.c.sc[tid]);
        out[tid * 5 + 0] = keep ? bx.x : 0.0f;
        out[tid * 5 + 1] = keep ? bx.y : 0.0f;
        out[tid * 5 + 2] = keep ? bx.z : 0.0f;
        out[tid * 5 + 3] = keep ? bx.w : 0.0f;
        out[tid * 5 + 4] = keep ? sc : 0.0f;
    }
}

extern "C" void kernel_launch(void* const* d_in, const int* in_sizes, int n_in,
                              void* d_out, int out_size, void* d_ws, size_t ws_size,
                              hipStream_t stream) {
    const float* logits = (const float*)d_in[0];
    const float* boxes  = (const float*)d_in[1];
    float* out = (float*)d_out;
    int nrows = in_sizes[0] / N_CLS;   // 200000

    char* w = (char*)d_ws;
    unsigned* cnt   = (unsigned*)(w + OFF_CNT);
    unsigned* ghist = (unsigned*)(w + OFF_GH);
    u64* sel        = (u64*)(w + OFF_SEL);

    hipMemsetAsync(w, 0, MEMSET_BYTES, stream);

    int nblk = (nrows + ROWS_PER_BLK - 1) / ROWS_PER_BLK;   // 1563
    k_pass1<<<nblk, 256, 0, stream>>>(logits, nrows, sel, cnt, ghist);
    k_tail<<<TAIL_BLOCKS, 1024, 0, stream>>>(w, boxes, out);
}